// Round 5
// baseline (463.063 us; speedup 1.0000x reference)
//
#include <hip/hip_runtime.h>
#include <hip/hip_bf16.h>

typedef __bf16 bf16;
typedef __bf16 bf16x4 __attribute__((ext_vector_type(4)));
typedef __bf16 bf16x8 __attribute__((ext_vector_type(8)));
typedef float floatx4 __attribute__((ext_vector_type(4)));
typedef float f32x2 __attribute__((ext_vector_type(2)));

#define FIN 128
#define HC 256          // H*C
#define HEADS 4
#define CDIM 64
#define BGRAPH 8
#define NEG 0.2f
#define EPS_GN 1e-5f
#define CAP 48          // max in-degree slot capacity; P(Poisson(12)>48)~1e-13/node

// R16: k3 fixes the two R15 defects quantified from counters:
//  (1) narrow 4B/lane gathers (1.84 TB/s delivered) -> 16B/lane dwordx4,
//      one instr covers 4 rows (lane l: bytes (l&15)*16 of row j+(l>>4))
//  (2) Wb epilogue re-read 64KB per 4-node block = 1.6GB L2 (~46us)
//      -> 16 nodes/block (4 waves x 4 serial nodes) = 400MB
//  Ybuf swizzle (u*16+nd)*16 ^ ((u&7)<<4): epilogue reads 1KB-contiguous.

__device__ __forceinline__ float lrelu(float v) { return v >= 0.f ? v : NEG * v; }
__device__ __forceinline__ float eexp(float v) { return __expf(fminf(v, 60.f)); }

__device__ __forceinline__ unsigned packbf(float a, float b) {
    unsigned short ua = __builtin_bit_cast(unsigned short, (bf16)a);
    unsigned short ub = __builtin_bit_cast(unsigned short, (bf16)b);
    return ((unsigned)ub << 16) | (unsigned)ua;
}

// ---- runtime dtype sniffs (wave-uniform, decided from data) ----------------
__device__ __forceinline__ bool sniff_i64(const int* __restrict__ p) {
    bool w64 = true;
#pragma unroll
    for (int i = 1; i < 16; i += 2) w64 = w64 && (p[i] == 0);
    return w64;
}
__device__ __forceinline__ bool sniff_f32(const void* __restrict__ xv) {
    const unsigned* u = (const unsigned*)xv;
    bool bf = true;
#pragma unroll
    for (int i = 0; i < 8; ++i) {
        unsigned lo = u[i] & 0xFFFFu;
        unsigned ex = (lo >> 7) & 0xFFu;
        bf = bf && ((ex >= 96u && ex <= 129u) || lo == 0u);
    }
    return !bf;   // true => data is fp32
}

__device__ __forceinline__ int gidx(const int* __restrict__ p, long long i,
                                    bool w64, int hi) {
    long long v = w64 ? ((const long long*)p)[i] : (long long)p[i];
    int x = (int)v;
    return x < 0 ? 0 : (x >= hi ? hi - 1 : x);
}

template <bool F32>
__device__ __forceinline__ float ldf(const void* __restrict__ p, int i) {
    if constexpr (F32) return ((const float*)p)[i];
    else               return (float)((const bf16*)p)[i];
}

template <bool F32>
__device__ __forceinline__ bf16x8 load8(const void* __restrict__ base, size_t off) {
    if constexpr (F32) {
        const float* p = (const float*)base + off;
        float4 a = *(const float4*)p, b = *(const float4*)(p + 4);
        bf16x8 r;
        r[0] = (bf16)a.x; r[1] = (bf16)a.y; r[2] = (bf16)a.z; r[3] = (bf16)a.w;
        r[4] = (bf16)b.x; r[5] = (bf16)b.y; r[6] = (bf16)b.z; r[7] = (bf16)b.w;
        return r;
    } else {
        return *(const bf16x8*)((const bf16*)base + off);
    }
}

// ---------------------------------------------------------------------------
// K1: transposed fused GEMM, single-stage 64KB W LDS, launch_bounds(256,2).
//     Stores Xb (bf16 cast of x) for k3's gather; att partials + residual
//     epilogue; zeroes cnt[]. (unchanged)
// ---------------------------------------------------------------------------
template <bool F32>
__device__ __forceinline__ void k1_impl(
        const void* __restrict__ x, const bf16x8* __restrict__ Wlds,
        const void* __restrict__ resW, const void* __restrict__ resB,
        const void* __restrict__ biasG,
        const bf16* __restrict__ aSc, const bf16* __restrict__ aDc,
        bf16* __restrict__ Xb, float* __restrict__ out_acc,
        float* __restrict__ a_src, float* __restrict__ a_dst, int N) {
    const int wave = threadIdx.x >> 6;
    const int lane = threadIdx.x & 63;
    const int nl = lane & 15;          // node within tile / D-col
    const int q  = lane >> 4;          // K-quad; D rows q*4..q*4+3
    const int base = blockIdx.x * 128 + wave * 32;

    bf16x8 xf[2][4];
    int nodes[2]; bool g[2];
#pragma unroll
    for (int nt = 0; nt < 2; ++nt) {
        int node = base + nt * 16 + nl;
        nodes[nt] = node; g[nt] = node < N;
        int cn = g[nt] ? node : N - 1;
#pragma unroll
        for (int kq = 0; kq < 4; ++kq)
            xf[nt][kq] = load8<F32>(x, (size_t)cn * FIN + kq * 32 + q * 8);
    }

    // emit Xb = bf16(x) rows for k3's gather
#pragma unroll
    for (int nt = 0; nt < 2; ++nt) {
        if (g[nt]) {
#pragma unroll
            for (int kq = 0; kq < 4; ++kq)
                *(bf16x8*)(Xb + (size_t)nodes[nt] * FIN + kq * 32 + q * 8) = xf[nt][kq];
        }
    }

    float s[2][4] = {{0,0,0,0},{0,0,0,0}};
    float d[2][4] = {{0,0,0,0},{0,0,0,0}};

#pragma unroll
    for (int tile = 0; tile < 16; ++tile) {
        bf16x8 wf[4];
#pragma unroll
        for (int kq = 0; kq < 4; ++kq)
            wf[kq] = Wlds[(tile * 4 + kq) * 64 + lane];
        const int e0 = tile * 16 + q * 4;   // e = e0 + r ; head h = e&3 = r
        bf16x4 sa = *(const bf16x4*)(aSc + e0);
        bf16x4 da = *(const bf16x4*)(aDc + e0);
#pragma unroll
        for (int nt = 0; nt < 2; ++nt) {
            floatx4 acc = {0,0,0,0};
#pragma unroll
            for (int kq = 0; kq < 4; ++kq)
                acc = __builtin_amdgcn_mfma_f32_16x16x32_bf16(wf[kq], xf[nt][kq], acc, 0, 0, 0);
#pragma unroll
            for (int r = 0; r < 4; ++r) {
                s[nt][r] += acc[r] * (float)sa[r];
                d[nt][r] += acc[r] * (float)da[r];
            }
        }
    }

    // ---- residual tiles (4 x 16 output channels), resW direct global ----
#pragma unroll
    for (int tile = 0; tile < 4; ++tile) {
        const int R = tile * 16 + nl;
        bf16x8 wf[4];
#pragma unroll
        for (int kq = 0; kq < 4; ++kq)
            wf[kq] = load8<F32>(resW, (size_t)R * FIN + kq * 32 + q * 8);
        const int c0 = tile * 16 + q * 4;
        const float b0 = ldf<F32>(resB, c0 + 0) + ldf<F32>(biasG, c0 + 0);
        const float b1 = ldf<F32>(resB, c0 + 1) + ldf<F32>(biasG, c0 + 1);
        const float b2 = ldf<F32>(resB, c0 + 2) + ldf<F32>(biasG, c0 + 2);
        const float b3 = ldf<F32>(resB, c0 + 3) + ldf<F32>(biasG, c0 + 3);
#pragma unroll
        for (int nt = 0; nt < 2; ++nt) {
            floatx4 acc = {0,0,0,0};
#pragma unroll
            for (int kq = 0; kq < 4; ++kq)
                acc = __builtin_amdgcn_mfma_f32_16x16x32_bf16(wf[kq], xf[nt][kq], acc, 0, 0, 0);
            float4 v = make_float4(acc[0] + b0, acc[1] + b1, acc[2] + b2, acc[3] + b3);
            if (g[nt]) *(float4*)(out_acc + (size_t)nodes[nt] * CDIM + c0) = v;
        }
    }

    // ---- reduce att partials across the 4 q-lanes, store from q==0 ----
#pragma unroll
    for (int off = 16; off <= 32; off <<= 1) {
#pragma unroll
        for (int nt = 0; nt < 2; ++nt)
#pragma unroll
            for (int r = 0; r < 4; ++r) {
                s[nt][r] += __shfl_xor(s[nt][r], off, 64);
                d[nt][r] += __shfl_xor(d[nt][r], off, 64);
            }
    }
    if (q == 0) {
#pragma unroll
        for (int nt = 0; nt < 2; ++nt) {
            if (g[nt]) {
                *(float4*)(a_src + (size_t)nodes[nt] * 4) =
                    make_float4(s[nt][0], s[nt][1], s[nt][2], s[nt][3]);
                *(float4*)(a_dst + (size_t)nodes[nt] * 4) =
                    make_float4(d[nt][0], d[nt][1], d[nt][2], d[nt][3]);
            }
        }
    }
}

__global__ __launch_bounds__(256, 2) void k1_gemm(
        const void* __restrict__ x, const void* __restrict__ W,
        const void* __restrict__ resW, const void* __restrict__ resB,
        const void* __restrict__ biasG, const void* __restrict__ attS,
        const void* __restrict__ attD,
        bf16* __restrict__ Xb, float* __restrict__ out_acc,
        float* __restrict__ a_src, float* __restrict__ a_dst,
        int* __restrict__ cnt, int N) {
    __shared__ bf16x8 Wlds[4096];   // 64 KB: W pre-permuted to fragment order
    __shared__ bf16 aSc[HC], aDc[HC];
    const bool f32 = sniff_f32(x);
    const int t = threadIdx.x;
    {   // fused kz: zero per-node edge counters (grid covers N)
        int gid = blockIdx.x * 256 + t;
        if (gid < N) cnt[gid] = 0;
    }
    {   // stage att channel-major: aSc[e] = attS[(e&3)*64 + (e>>2)]
        int src = (t & 3) * 64 + (t >> 2);
        aSc[t] = f32 ? (bf16)((const float*)attS)[src] : ((const bf16*)attS)[src];
        aDc[t] = f32 ? (bf16)((const float*)attD)[src] : ((const bf16*)attD)[src];
    }
    if (f32) {
#pragma unroll
        for (int j = 0; j < 16; ++j) {
            int i = t + j * 256;
            int tileq = i >> 6, lane = i & 63;
            int tile = tileq >> 2, kq = tileq & 3;
            int R = tile * 16 + (lane & 15);
            size_t off = (size_t)((R & 3) * 64 + (R >> 2)) * FIN + kq * 32 + (lane >> 4) * 8;
            Wlds[i] = load8<true>(W, off);
        }
    } else {
#pragma unroll
        for (int j = 0; j < 16; ++j) {
            int i = t + j * 256;
            int tileq = i >> 6, lane = i & 63;
            int tile = tileq >> 2, kq = tileq & 3;
            int R = tile * 16 + (lane & 15);
            size_t off = (size_t)((R & 3) * 64 + (R >> 2)) * FIN + kq * 32 + (lane >> 4) * 8;
            Wlds[i] = load8<false>(W, off);
        }
    }
    __syncthreads();
    if (f32) k1_impl<true >(x, Wlds, resW, resB, biasG, aSc, aDc, Xb, out_acc, a_src, a_dst, N);
    else     k1_impl<false>(x, Wlds, resW, resB, biasG, aSc, aDc, Xb, out_acc, a_src, a_dst, N);
}

// ---------------------------------------------------------------------------
// KSCAT: single-pass capacity-CSR build (cnt zeroed by k1).
//   First 16 blocks also convert W -> Wb (bf16, k3-epilogue fragment order).
// ---------------------------------------------------------------------------
__global__ __launch_bounds__(256) void kscat(
        const int* __restrict__ ei, int* __restrict__ cnt,
        int* __restrict__ adj, const void* __restrict__ W,
        bf16* __restrict__ Wb, int E, int N) {
    const int b = blockIdx.x, t = threadIdx.x;
    if (b < 16) {
        const bool f32 = sniff_f32(W);
        int f0 = (b * 256 + t) * 8;          // 0..32760
        int tw = f0 >> 9;                     // (t*4+wid), 0..63
        int ln = (f0 >> 3) & 63;
        int tt = tw >> 2, wd = tw & 3;
        int row = (tt >> 2) * 64 + wd * 16 + (ln & 15);
        int col = (tt & 3) * 32 + (ln >> 4) * 8;
        bf16x8 v = f32 ? load8<true>(W, (size_t)row * FIN + col)
                       : load8<false>(W, (size_t)row * FIN + col);
        *(bf16x8*)(Wb + f0) = v;
    }
    int e = b * 256 + t;
    if (e >= E) return;
    bool w64 = sniff_i64(ei);
    int s = gidx(ei, e, w64, N);
    int d = gidx(ei, (long long)E + e, w64, N);
    int pos = atomicAdd(&cnt[d], 1);
    if (pos < CAP) adj[(size_t)d * CAP + pos] = s;
}

// ---------------------------------------------------------------------------
// K3 (R16): 16 nodes/block, 4 waves, 4 serial nodes/wave.
//   Gather: lane l loads bytes (l&15)*16 of row j+(l>>4) -> 1 dwordx4 instr
//   covers 4 rows (1KB). acc[4head][4pair] f32x2; butterfly xor16/32 across
//   row-groups; head-select; one swizzled b128 Ybuf write per node.
//   Epilogue: 16-row MFMA, A = 16 real nodes (Wb traffic amortized 4x).
// ---------------------------------------------------------------------------
__global__ __launch_bounds__(256, 4) void k3_fused(
        const int* __restrict__ cnt, const int* __restrict__ adj,
        const float* __restrict__ a_src, const float* __restrict__ a_dst,
        const bf16* __restrict__ Xb, const bf16* __restrict__ Wb,
        float* __restrict__ out_acc, int N) {
    __shared__ float4 sh_w4[16][64];     // 16 KB normalized weights
    __shared__ int    sh_off[16][64];    // 4 KB row byte offsets (s*256)
    __shared__ char   Ybuf[16384];       // 16 KB Y[16 nodes][512 bf16] swizzled
    const int wid  = threadIdx.x >> 6;
    const int lane = threadIdx.x & 63;
    const int g    = lane >> 4;                       // row-group
    const unsigned cb = (unsigned)(lane & 15) * 16;   // channel-byte offset

#pragma unroll 1
    for (int uu = 0; uu < 4; ++uu) {
        const int nd = wid * 4 + uu;
        const int n = blockIdx.x * 16 + nd;
        const unsigned ybase = (((unsigned)lane * 16 + (unsigned)nd) * 16)
                             ^ (((unsigned)lane & 7u) << 4);
        if (n >= N) {
            *(uint4*)(Ybuf + ybase) = (uint4){0, 0, 0, 0};
            continue;
        }
        int cn = cnt[n]; if (cn > CAP) cn = CAP;
        const float4 ad  = *(const float4*)(a_dst + (size_t)n * 4);
        const float4 asn = *(const float4*)(a_src + (size_t)n * 4);
        const float e0 = eexp(lrelu(asn.x + ad.x));
        const float e1 = eexp(lrelu(asn.y + ad.y));
        const float e2 = eexp(lrelu(asn.z + ad.z));
        const float e3 = eexp(lrelu(asn.w + ad.w));

        float w0 = 0.f, w1 = 0.f, w2 = 0.f, w3 = 0.f;
        float d0 = 0.f, d1 = 0.f, d2 = 0.f, d3 = 0.f;
        int s_all = n;
        if (lane < cn) {
            s_all = adj[(size_t)n * CAP + lane];
            float4 as = *(const float4*)(a_src + (size_t)s_all * 4);
            w0 = eexp(lrelu(as.x + ad.x));
            w1 = eexp(lrelu(as.y + ad.y));
            w2 = eexp(lrelu(as.z + ad.z));
            w3 = eexp(lrelu(as.w + ad.w));
            d0 = w0; d1 = w1; d2 = w2; d3 = w3;
        }
#pragma unroll
        for (int off = 1; off <= 32; off <<= 1) {
            d0 += __shfl_xor(d0, off, 64);
            d1 += __shfl_xor(d1, off, 64);
            d2 += __shfl_xor(d2, off, 64);
            d3 += __shfl_xor(d3, off, 64);
        }
        d0 += e0; d1 += e1; d2 += e2; d3 += e3;
        const float i0 = 0.25f * __builtin_amdgcn_rcpf(d0);
        const float i1 = 0.25f * __builtin_amdgcn_rcpf(d1);
        const float i2 = 0.25f * __builtin_amdgcn_rcpf(d2);
        const float i3 = 0.25f * __builtin_amdgcn_rcpf(d3);

        if (lane < cn) {
            sh_w4[nd][lane] = make_float4(w0 * i0, w1 * i1, w2 * i2, w3 * i3);
            sh_off[nd][lane] = s_all << 8;            // s * 128 * 2B
        } else if (lane == cn) {                      // self-loop as slot cn
            sh_w4[nd][lane] = make_float4(e0 * i0, e1 * i1, e2 * i2, e3 * i3);
            sh_off[nd][lane] = n << 8;
        }
        const int m = cn + 1;

        f32x2 acc[4][4];
#pragma unroll
        for (int h = 0; h < 4; ++h)
#pragma unroll
            for (int p = 0; p < 4; ++p) { acc[h][p][0] = 0.f; acc[h][p][1] = 0.f; }

#define K3ACC(rv, wv) do {                                                  \
        _Pragma("unroll")                                                   \
        for (int p = 0; p < 4; ++p) {                                       \
            unsigned rp = (p == 0 ? (rv).x : p == 1 ? (rv).y                \
                         : p == 2 ? (rv).z : (rv).w);                       \
            f32x2 xv;                                                       \
            xv[0] = __builtin_bit_cast(float, rp << 16);                    \
            xv[1] = __builtin_bit_cast(float, rp & 0xFFFF0000u);            \
            acc[0][p] += (wv).x * xv;                                       \
            acc[1][p] += (wv).y * xv;                                       \
            acc[2][p] += (wv).z * xv;                                       \
            acc[3][p] += (wv).w * xv;                                       \
        }                                                                   \
    } while (0)

        int j = 0;
        for (; j + 8 <= m; j += 8) {        // 2 wide instrs = 8 rows in flight
            unsigned oA = (unsigned)sh_off[nd][j + g];
            unsigned oB = (unsigned)sh_off[nd][j + 4 + g];
            uint4 rA = *(const uint4*)((const char*)Xb + (oA + cb));
            uint4 rB = *(const uint4*)((const char*)Xb + (oB + cb));
            float4 wA = sh_w4[nd][j + g];
            float4 wB = sh_w4[nd][j + 4 + g];
            K3ACC(rA, wA);
            K3ACC(rB, wB);
        }
        if (j + 4 <= m) {
            unsigned oA = (unsigned)sh_off[nd][j + g];
            uint4 rA = *(const uint4*)((const char*)Xb + (oA + cb));
            float4 wA = sh_w4[nd][j + g];
            K3ACC(rA, wA);
            j += 4;
        }
        if (j < m && g < m - j) {           // tail rows (<4): groups g<rem
            unsigned oA = (unsigned)sh_off[nd][j + g];
            uint4 rA = *(const uint4*)((const char*)Xb + (oA + cb));
            float4 wA = sh_w4[nd][j + g];
            K3ACC(rA, wA);
        }
#undef K3ACC

        // reduce across the 4 row-groups (xor 16, 32)
#pragma unroll
        for (int h = 0; h < 4; ++h)
#pragma unroll
            for (int p = 0; p < 4; ++p) {
                float a0 = acc[h][p][0], a1 = acc[h][p][1];
                a0 += __shfl_xor(a0, 16, 64); a1 += __shfl_xor(a1, 16, 64);
                a0 += __shfl_xor(a0, 32, 64); a1 += __shfl_xor(a1, 32, 64);
                acc[h][p][0] = a0; acc[h][p][1] = a1;
            }
        // lane keeps head g; pack 8 channels -> one b128 swizzled write
        f32x2 y0 = acc[0][0], y1 = acc[0][1], y2 = acc[0][2], y3 = acc[0][3];
        y0 = (g == 1) ? acc[1][0] : y0;  y1 = (g == 1) ? acc[1][1] : y1;
        y2 = (g == 1) ? acc[1][2] : y2;  y3 = (g == 1) ? acc[1][3] : y3;
        y0 = (g == 2) ? acc[2][0] : y0;  y1 = (g == 2) ? acc[2][1] : y1;
        y2 = (g == 2) ? acc[2][2] : y2;  y3 = (g == 2) ? acc[2][3] : y3;
        y0 = (g == 3) ? acc[3][0] : y0;  y1 = (g == 3) ? acc[3][1] : y1;
        y2 = (g == 3) ? acc[3][2] : y2;  y3 = (g == 3) ? acc[3][3] : y3;
        uint4 pk;
        pk.x = packbf(y0[0], y0[1]);
        pk.y = packbf(y1[0], y1[1]);
        pk.z = packbf(y2[0], y2[1]);
        pk.w = packbf(y3[0], y3[1]);
        *(uint4*)(Ybuf + ybase) = pk;
    }
    __syncthreads();

    // ---- epilogue: C[node][c] = sum_{K'} Y[node][K'] * Wb, 16 real rows ---
    const int nl = lane & 15, q = lane >> 4;
    floatx4 cacc = {0.f, 0.f, 0.f, 0.f};
#pragma unroll
    for (int t = 0; t < 16; ++t) {
        const unsigned ua = (unsigned)(t * 4 + q);
        const unsigned aoff = ((ua * 16 + (unsigned)nl) * 16) ^ ((ua & 7u) << 4);
        bf16x8 af = *(const bf16x8*)(Ybuf + aoff);
        bf16x8 bfr = *(const bf16x8*)(Wb + ((size_t)((t * 4 + wid) * 64 + lane)) * 8);
        cacc = __builtin_amdgcn_mfma_f32_16x16x32_bf16(af, bfr, cacc, 0, 0, 0);
    }
#pragma unroll
    for (int r = 0; r < 4; ++r) {
        int nn = blockIdx.x * 16 + q * 4 + r;
        if (nn < N) {
            float* p = out_acc + (size_t)nn * CDIM + wid * 16 + nl;
            *p += cacc[r];      // seeded with residual + biases
        }
    }
}

// ---------------------------------------------------------------------------
// K4: GraphNorm partial sums — atomic-free (R9-proven).
// ---------------------------------------------------------------------------
__global__ __launch_bounds__(256) void k4_stats(
        const float* __restrict__ out_acc, const int* __restrict__ batch,
        const int* __restrict__ ei,
        float* __restrict__ pS1, float* __restrict__ pS2, int N) {
    __shared__ float p1[4][BGRAPH][64], p2[4][BGRAPH][64];
    const int w = threadIdx.x >> 6;
    const int c = threadIdx.x & 63;
#pragma unroll
    for (int k = threadIdx.x; k < 4 * BGRAPH * 64; k += 256) {
        ((float*)p1)[k] = 0.f; ((float*)p2)[k] = 0.f;
    }
    __syncthreads();
    bool w64 = sniff_i64(ei);
    const int n0 = blockIdx.x * 256 + w * 64;
    float ls1 = 0.f, ls2 = 0.f;
    int curb = -1;
    for (int i = 0; i < 64; ++i) {
        int n = n0 + i;
        if (n >= N) break;
        float hv = out_acc[(size_t)n * CDIM + c];
        int b = gidx(batch, n, w64, BGRAPH);
        if (b != curb) {
            if (curb >= 0) { p1[w][curb][c] += ls1; p2[w][curb][c] += ls2; }
            curb = b; ls1 = 0.f; ls2 = 0.f;
        }
        ls1 += hv; ls2 += hv * hv;
    }
    if (curb >= 0) { p1[w][curb][c] += ls1; p2[w][curb][c] += ls2; }
    __syncthreads();
    for (int k = threadIdx.x; k < BGRAPH * 64; k += 256) {
        int b = k >> 6, cc = k & 63;
        pS1[(size_t)blockIdx.x * (BGRAPH * 64) + k] =
            p1[0][b][cc] + p1[1][b][cc] + p1[2][b][cc] + p1[3][b][cc];
        pS2[(size_t)blockIdx.x * (BGRAPH * 64) + k] =
            p2[0][b][cc] + p2[1][b][cc] + p2[2][b][cc] + p2[3][b][cc];
    }
}

// ---------------------------------------------------------------------------
// KR: fold block partials into S1/S2 (8 blocks, one per graph) + start[]
// ---------------------------------------------------------------------------
__global__ __launch_bounds__(256) void kr_reduce(
        const float* __restrict__ pS1, const float* __restrict__ pS2,
        float* __restrict__ S1, float* __restrict__ S2,
        const int* __restrict__ batch, const int* __restrict__ ei,
        int* __restrict__ start, int nblk, int N) {
    __shared__ float r1[4][64], r2[4][64];
    const int b = blockIdx.x;
    const int seg = threadIdx.x >> 6;
    const int c = threadIdx.x & 63;
    float s1 = 0.f, s2 = 0.f;
    for (int blk = seg; blk < nblk; blk += 4) {
        s1 += pS1[(size_t)blk * (BGRAPH * 64) + b * 64 + c];
        s2 += pS2[(size_t)blk * (BGRAPH * 64) + b * 64 + c];
    }
    r1[seg][c] = s1; r2[seg][c] = s2;
    __syncthreads();
    if (seg == 0) {
        S1[b * 64 + c] = r1[0][c] + r1[1][c] + r1[2][c] + r1[3][c];
        S2[b * 64 + c] = r2[0][c] + r2[1][c] + r2[2][c] + r2[3][c];
    }
    if (b == 0 && threadIdx.x <= BGRAPH) {
        int t = threadIdx.x;
        bool w64 = sniff_i64(ei);
        int lo = 0, hi = N;
        while (lo < hi) {
            int mid = (lo + hi) >> 1;
            long long bv = w64 ? ((const long long*)batch)[mid] : (long long)batch[mid];
            if (bv < t) lo = mid + 1; else hi = mid;
        }
        start[t] = lo;
    }
}

// ---------------------------------------------------------------------------
// K6: GraphNorm + GELU(tanh approx) -> out (dtype per sniff)
// ---------------------------------------------------------------------------
template <bool F32>
__device__ __forceinline__ void k6_impl(
        const float* __restrict__ out_acc, const int* __restrict__ batch,
        bool w64,
        const float* __restrict__ S1, const float* __restrict__ S2,
        const int* __restrict__ start, const void* __restrict__ gw,
        const void* __restrict__ gb, const void* __restrict__ msc,
        void* __restrict__ out, int N) {
    int idx = blockIdx.x * 256 + threadIdx.x;
    if (idx >= N * CDIM) return;
    int n = idx >> 6, c = idx & 63;
    int b = gidx(batch, n, w64, BGRAPH);
    int cnt_i = start[b + 1] - start[b];
    float cnt = (float)(cnt_i < 1 ? 1 : cnt_i);
    float m = S1[b * CDIM + c] / cnt;
    float ms = ldf<F32>(msc, c);
    float var = S2[b * CDIM + c] / cnt + m * m * ms * (ms - 2.0f);
    float centered = out_acc[idx] - m * ms;
    float normed = ldf<F32>(gw, c) * centered * rsqrtf(fmaxf(var, 0.f) + EPS_GN)
                   + ldf<F32>(gb, c);
    float t = 0.7978845608028654f * (normed + 0.044715f * normed * normed * normed);
    float gel = 0.5f * normed * (1.0f + tanhf(t));
    if constexpr (F32) ((float*)out)[idx] = gel;
    else               ((bf16*)out)[idx] = (bf16)gel;
}

__global__ __launch_bounds__(256) void k6_norm(
        const void* __restrict__ xsniff,
        const float* __restrict__ out_acc, const int* __restrict__ batch,
        const int* __restrict__ ei,
        const float* __restrict__ S1, const float* __restrict__ S2,
        const int* __restrict__ start, const void* __restrict__ gw,
        const void* __restrict__ gb, const void* __restrict__ msc,
        void* __restrict__ out, int N) {
    bool w64 = sniff_i64(ei);
    if (sniff_f32(xsniff))
        k6_impl<true >(out_acc, batch, w64, S1, S2, start, gw, gb, msc, out, N);
    else
        k6_impl<false>(out_acc, batch, w64, S1, S2, start, gw, gb, msc, out, N);
}

// ---------------------------------------------------------------------------
extern "C" void kernel_launch(void* const* d_in, const int* in_sizes, int n_in,
                              void* d_out, int out_size, void* d_ws, size_t ws_size,
                              hipStream_t stream) {
    const void* x     = d_in[0];
    const int*  ei    = (const int*)d_in[1];
    const int*  batch = (const int*)d_in[2];
    const void* W     = d_in[3];
    const void* attS  = d_in[4];
    const void* attD  = d_in[5];
    const void* biasG = d_in[6];
    const void* resW  = d_in[7];
    const void* resB  = d_in[8];
    const void* gw    = d_in[9];
    const void* gb    = d_in[10];
    const void* msc   = d_in[11];

    const int N = in_sizes[0] / FIN;
    const int E = in_sizes[1] / 2;
    const int NB = (N + 255) / 256;    // 256-node blocks (k4)

    char* ws = (char*)d_ws;
    size_t off = 0;
    auto alloc = [&](size_t bytes) { char* p = ws + off; off = (off + bytes + 255) & ~(size_t)255; return p; };
    bf16*  Xb      = (bf16*) alloc((size_t)N * FIN * sizeof(bf16));
    float* out_acc = (float*)alloc((size_t)N * CDIM * sizeof(float));
    float* a_src   = (float*)alloc((size_t)N * HEADS * sizeof(float));
    float* a_dst   = (float*)alloc((size_t)N * HEADS * sizeof(float));
    int*   cnt     = (int*)  alloc((size_t)N * sizeof(int));
    int*   adj     = (int*)  alloc((size_t)N * CAP * sizeof(int));
    bf16*  Wb      = (bf16*) alloc((size_t)HC * FIN * sizeof(bf16));   // 64 KB
    float* pS1     = (float*)alloc((size_t)NB * BGRAPH * 64 * sizeof(float));
    float* pS2     = (float*)alloc((size_t)NB * BGRAPH * 64 * sizeof(float));
    float* S1      = (float*)alloc(BGRAPH * CDIM * sizeof(float));
    float* S2      = (float*)alloc(BGRAPH * CDIM * sizeof(float));
    int*   start   = (int*)  alloc((BGRAPH + 1) * sizeof(int));

    hipLaunchKernelGGL(k1_gemm, dim3((N + 127) / 128), dim3(256), 0, stream,
                       x, W, resW, resB, biasG, attS, attD, Xb, out_acc, a_src, a_dst, cnt, N);
    hipLaunchKernelGGL(kscat, dim3((E + 255) / 256), dim3(256), 0, stream,
                       ei, cnt, adj, W, Wb, E, N);
    hipLaunchKernelGGL(k3_fused, dim3((N + 15) / 16), dim3(256), 0, stream,
                       cnt, adj, a_src, a_dst, Xb, Wb, out_acc, N);
    hipLaunchKernelGGL(k4_stats, dim3(NB), dim3(256), 0, stream,
                       out_acc, batch, ei, pS1, pS2, N);
    hipLaunchKernelGGL(kr_reduce, dim3(BGRAPH), dim3(256), 0, stream,
                       pS1, pS2, S1, S2, batch, ei, start, NB, N);
    hipLaunchKernelGGL(k6_norm, dim3((N * CDIM + 255) / 256), dim3(256), 0, stream,
                       x, out_acc, batch, ei, S1, S2, start, gw, gb, msc, d_out, N);
}

// Round 7
// 372.065 us; speedup vs baseline: 1.2446x; 1.2446x over previous
//
#include <hip/hip_runtime.h>
#include <hip/hip_bf16.h>

typedef __bf16 bf16;
typedef __bf16 bf16x4 __attribute__((ext_vector_type(4)));
typedef __bf16 bf16x8 __attribute__((ext_vector_type(8)));
typedef float floatx4 __attribute__((ext_vector_type(4)));
typedef _Float16 f16;
typedef _Float16 f16x4 __attribute__((ext_vector_type(4)));
typedef _Float16 h2 __attribute__((ext_vector_type(2)));

#define FIN 128
#define HC 256          // H*C
#define HEADS 4
#define CDIM 64
#define BGRAPH 8
#define NEG 0.2f
#define EPS_GN 1e-5f
#define CAP 48          // max in-degree slot capacity; P(Poisson(12)>48)~1e-13/node

// R18 == R17 with hipMemsetAsync replaced by kz_zero kernel (suspected
// graph-capture tripwire -> container failed twice). Structure:
//  - kz_zero: cnt + S1 + S2 (one word/thread)
//  - k1: GEMM blocks + trailing edge-scatter blocks (kscat fused; overlap)
//  - k3: R13-proven gather kernel (107us floor, 5 structures tested R12-R16)
//  - k4: partials + atomic fold into S1/S2 + start[] (kr eliminated)
//  - k6: GraphNorm + GELU

__device__ __forceinline__ float lrelu(float v) { return v >= 0.f ? v : NEG * v; }
__device__ __forceinline__ float eexp(float v) { return __expf(fminf(v, 60.f)); }

__device__ __forceinline__ float dot2h(h2 a, h2 b, float c) {
#if __has_builtin(__builtin_amdgcn_fdot2)
    return __builtin_amdgcn_fdot2(a, b, c, false);
#else
    return c + (float)a[0] * (float)b[0] + (float)a[1] * (float)b[1];
#endif
}
__device__ __forceinline__ h2 bch2(unsigned u) { return __builtin_bit_cast(h2, u); }

// ---- runtime dtype sniffs (wave-uniform, decided from data) ----------------
__device__ __forceinline__ bool sniff_i64(const int* __restrict__ p) {
    bool w64 = true;
#pragma unroll
    for (int i = 1; i < 16; i += 2) w64 = w64 && (p[i] == 0);
    return w64;
}
__device__ __forceinline__ bool sniff_f32(const void* __restrict__ xv) {
    const unsigned* u = (const unsigned*)xv;
    bool bf = true;
#pragma unroll
    for (int i = 0; i < 8; ++i) {
        unsigned lo = u[i] & 0xFFFFu;
        unsigned ex = (lo >> 7) & 0xFFu;
        bf = bf && ((ex >= 96u && ex <= 129u) || lo == 0u);
    }
    return !bf;   // true => data is fp32
}

__device__ __forceinline__ int gidx(const int* __restrict__ p, long long i,
                                    bool w64, int hi) {
    long long v = w64 ? ((const long long*)p)[i] : (long long)p[i];
    int x = (int)v;
    return x < 0 ? 0 : (x >= hi ? hi - 1 : x);
}

template <bool F32>
__device__ __forceinline__ float ldf(const void* __restrict__ p, int i) {
    if constexpr (F32) return ((const float*)p)[i];
    else               return (float)((const bf16*)p)[i];
}

template <bool F32>
__device__ __forceinline__ bf16x8 load8(const void* __restrict__ base, size_t off) {
    if constexpr (F32) {
        const float* p = (const float*)base + off;
        float4 a = *(const float4*)p, b = *(const float4*)(p + 4);
        bf16x8 r;
        r[0] = (bf16)a.x; r[1] = (bf16)a.y; r[2] = (bf16)a.z; r[3] = (bf16)a.w;
        r[4] = (bf16)b.x; r[5] = (bf16)b.y; r[6] = (bf16)b.z; r[7] = (bf16)b.w;
        return r;
    } else {
        return *(const bf16x8*)((const bf16*)base + off);
    }
}

// ---------------------------------------------------------------------------
// KZ: zero cnt[N] + S1[512] + S2[512] (workspace may be poisoned per run)
// ---------------------------------------------------------------------------
__global__ __launch_bounds__(256) void kz_zero(
        int* __restrict__ cnt, float* __restrict__ S1,
        float* __restrict__ S2, int N) {
    int i = blockIdx.x * 256 + threadIdx.x;
    if (i < N) cnt[i] = 0;
    if (i < BGRAPH * CDIM) { S1[i] = 0.f; S2[i] = 0.f; }
}

// ---------------------------------------------------------------------------
// K1 (fused with kscat): first NB1 blocks do the transposed fused GEMM
//     (R13-proven: f16 xl, att partials, residual epilogue); remaining
//     blocks scatter edges into capacity-CSR (cnt pre-zeroed by kz).
// ---------------------------------------------------------------------------
template <bool F32>
__device__ __forceinline__ void k1_impl(
        const void* __restrict__ x, const bf16x8* __restrict__ Wlds,
        const void* __restrict__ resW, const void* __restrict__ resB,
        const void* __restrict__ biasG,
        const bf16* __restrict__ aSc, const bf16* __restrict__ aDc,
        f16* __restrict__ xl, float* __restrict__ out_acc,
        float* __restrict__ a_src, float* __restrict__ a_dst, int N) {
    const int wave = threadIdx.x >> 6;
    const int lane = threadIdx.x & 63;
    const int nl = lane & 15;          // node within tile / D-col
    const int q  = lane >> 4;          // K-quad; D rows q*4..q*4+3
    const int base = blockIdx.x * 128 + wave * 32;

    bf16x8 xf[2][4];
    int nodes[2]; bool g[2];
#pragma unroll
    for (int nt = 0; nt < 2; ++nt) {
        int node = base + nt * 16 + nl;
        nodes[nt] = node; g[nt] = node < N;
        int cn = g[nt] ? node : N - 1;
#pragma unroll
        for (int kq = 0; kq < 4; ++kq)
            xf[nt][kq] = load8<F32>(x, (size_t)cn * FIN + kq * 32 + q * 8);
    }

    float s[2][4] = {{0,0,0,0},{0,0,0,0}};
    float d[2][4] = {{0,0,0,0},{0,0,0,0}};

#pragma unroll
    for (int tile = 0; tile < 16; ++tile) {
        bf16x8 wf[4];
#pragma unroll
        for (int kq = 0; kq < 4; ++kq)
            wf[kq] = Wlds[(tile * 4 + kq) * 64 + lane];
        const int e0 = tile * 16 + q * 4;   // e = e0 + r ; head h = e&3 = r
        bf16x4 sa = *(const bf16x4*)(aSc + e0);
        bf16x4 da = *(const bf16x4*)(aDc + e0);
#pragma unroll
        for (int nt = 0; nt < 2; ++nt) {
            floatx4 acc = {0,0,0,0};
#pragma unroll
            for (int kq = 0; kq < 4; ++kq)
                acc = __builtin_amdgcn_mfma_f32_16x16x32_bf16(wf[kq], xf[nt][kq], acc, 0, 0, 0);
            f16x4 p;
#pragma unroll
            for (int r = 0; r < 4; ++r) {
                p[r] = (f16)acc[r];
                s[nt][r] += acc[r] * (float)sa[r];
                d[nt][r] += acc[r] * (float)da[r];
            }
            if (g[nt]) *(f16x4*)(xl + (size_t)nodes[nt] * HC + e0) = p;
        }
    }

    // ---- residual tiles (4 x 16 output channels), resW direct global ----
#pragma unroll
    for (int tile = 0; tile < 4; ++tile) {
        const int R = tile * 16 + nl;
        bf16x8 wf[4];
#pragma unroll
        for (int kq = 0; kq < 4; ++kq)
            wf[kq] = load8<F32>(resW, (size_t)R * FIN + kq * 32 + q * 8);
        const int c0 = tile * 16 + q * 4;
        const float b0 = ldf<F32>(resB, c0 + 0) + ldf<F32>(biasG, c0 + 0);
        const float b1 = ldf<F32>(resB, c0 + 1) + ldf<F32>(biasG, c0 + 1);
        const float b2 = ldf<F32>(resB, c0 + 2) + ldf<F32>(biasG, c0 + 2);
        const float b3 = ldf<F32>(resB, c0 + 3) + ldf<F32>(biasG, c0 + 3);
#pragma unroll
        for (int nt = 0; nt < 2; ++nt) {
            floatx4 acc = {0,0,0,0};
#pragma unroll
            for (int kq = 0; kq < 4; ++kq)
                acc = __builtin_amdgcn_mfma_f32_16x16x32_bf16(wf[kq], xf[nt][kq], acc, 0, 0, 0);
            float4 v = make_float4(acc[0] + b0, acc[1] + b1, acc[2] + b2, acc[3] + b3);
            if (g[nt]) *(float4*)(out_acc + (size_t)nodes[nt] * CDIM + c0) = v;
        }
    }

    // ---- reduce att partials across the 4 q-lanes, store from q==0 ----
#pragma unroll
    for (int off = 16; off <= 32; off <<= 1) {
#pragma unroll
        for (int nt = 0; nt < 2; ++nt)
#pragma unroll
            for (int r = 0; r < 4; ++r) {
                s[nt][r] += __shfl_xor(s[nt][r], off, 64);
                d[nt][r] += __shfl_xor(d[nt][r], off, 64);
            }
    }
    if (q == 0) {
#pragma unroll
        for (int nt = 0; nt < 2; ++nt) {
            if (g[nt]) {
                *(float4*)(a_src + (size_t)nodes[nt] * 4) =
                    make_float4(s[nt][0], s[nt][1], s[nt][2], s[nt][3]);
                *(float4*)(a_dst + (size_t)nodes[nt] * 4) =
                    make_float4(d[nt][0], d[nt][1], d[nt][2], d[nt][3]);
            }
        }
    }
}

__global__ __launch_bounds__(256, 2) void k1_gemm(
        const void* __restrict__ x, const void* __restrict__ W,
        const void* __restrict__ resW, const void* __restrict__ resB,
        const void* __restrict__ biasG, const void* __restrict__ attS,
        const void* __restrict__ attD,
        f16* __restrict__ xl, float* __restrict__ out_acc,
        float* __restrict__ a_src, float* __restrict__ a_dst,
        const int* __restrict__ ei, int* __restrict__ cnt,
        int* __restrict__ adj, int NB1, int E, int N) {
    __shared__ bf16x8 Wlds[4096];   // 64 KB: W pre-permuted to fragment order
    __shared__ bf16 aSc[HC], aDc[HC];
    const int t = threadIdx.x;

    if (blockIdx.x >= NB1) {
        // ---- scatter blocks: capacity-CSR build, 4 edges/thread ----
        const long long base = (long long)(blockIdx.x - NB1) * 1024;
        const bool w64 = sniff_i64(ei);
#pragma unroll
        for (int u = 0; u < 4; ++u) {
            long long e = base + u * 256 + t;
            if (e < E) {
                int s = gidx(ei, e, w64, N);
                int d = gidx(ei, (long long)E + e, w64, N);
                int pos = atomicAdd(&cnt[d], 1);
                if (pos < CAP) adj[(size_t)d * CAP + pos] = s;
            }
        }
        return;
    }

    const bool f32 = sniff_f32(x);
    {   // stage att channel-major: aSc[e] = attS[(e&3)*64 + (e>>2)]
        int src = (t & 3) * 64 + (t >> 2);
        aSc[t] = f32 ? (bf16)((const float*)attS)[src] : ((const bf16*)attS)[src];
        aDc[t] = f32 ? (bf16)((const float*)attD)[src] : ((const bf16*)attD)[src];
    }
    if (f32) {
#pragma unroll
        for (int j = 0; j < 16; ++j) {
            int i = t + j * 256;
            int tileq = i >> 6, lane = i & 63;
            int tile = tileq >> 2, kq = tileq & 3;
            int R = tile * 16 + (lane & 15);
            size_t off = (size_t)((R & 3) * 64 + (R >> 2)) * FIN + kq * 32 + (lane >> 4) * 8;
            Wlds[i] = load8<true>(W, off);
        }
    } else {
#pragma unroll
        for (int j = 0; j < 16; ++j) {
            int i = t + j * 256;
            int tileq = i >> 6, lane = i & 63;
            int tile = tileq >> 2, kq = tileq & 3;
            int R = tile * 16 + (lane & 15);
            size_t off = (size_t)((R & 3) * 64 + (R >> 2)) * FIN + kq * 32 + (lane >> 4) * 8;
            Wlds[i] = load8<false>(W, off);
        }
    }
    __syncthreads();
    if (f32) k1_impl<true >(x, Wlds, resW, resB, biasG, aSc, aDc, xl, out_acc, a_src, a_dst, N);
    else     k1_impl<false>(x, Wlds, resW, resB, biasG, aSc, aDc, xl, out_acc, a_src, a_dst, N);
}

// ---------------------------------------------------------------------------
// K3: fused softmax + aggregation over capacity-CSR. One wave per node.
//     R13-proven kernel: f16 xl + fdot2, half-wave dwordx4 row loads,
//     pre-normalized f16 weights, self-loop as edge slot cn. 107us, occ 80%.
// ---------------------------------------------------------------------------
__global__ __launch_bounds__(256) void k3_fused(
        const int* __restrict__ cnt, const int* __restrict__ adj,
        const float* __restrict__ a_src, const float* __restrict__ a_dst,
        const f16* __restrict__ xl, float* __restrict__ out_acc, int N) {
    __shared__ unsigned sh_w[4][64][2];   // normalized f16x4 weights per entry
    __shared__ int      sh_off[4][64];    // row byte offsets (s*512)
    const int wid  = threadIdx.x >> 6;
    const int lane = threadIdx.x & 63;
    const int n = blockIdx.x * 4 + wid;
    if (n >= N) return;
    int cn = cnt[n]; if (cn > CAP) cn = CAP;
    const float4 ad  = *(const float4*)(a_dst + (size_t)n * 4);
    const float4 asn = *(const float4*)(a_src + (size_t)n * 4);
    const float e0 = eexp(lrelu(asn.x + ad.x));
    const float e1 = eexp(lrelu(asn.y + ad.y));
    const float e2 = eexp(lrelu(asn.z + ad.z));
    const float e3 = eexp(lrelu(asn.w + ad.w));

    float w0 = 0.f, w1 = 0.f, w2 = 0.f, w3 = 0.f;
    float d0 = 0.f, d1 = 0.f, d2 = 0.f, d3 = 0.f;
    int s = 0;
    if (lane < cn) {
        s = adj[(size_t)n * CAP + lane];
        float4 as = *(const float4*)(a_src + (size_t)s * 4);
        w0 = eexp(lrelu(as.x + ad.x));
        w1 = eexp(lrelu(as.y + ad.y));
        w2 = eexp(lrelu(as.z + ad.z));
        w3 = eexp(lrelu(as.w + ad.w));
        d0 = w0; d1 = w1; d2 = w2; d3 = w3;
    }
    // wave-reduce denominators, add self, fold 0.25 head-mean into inverse
#pragma unroll
    for (int off = 1; off <= 32; off <<= 1) {
        d0 += __shfl_xor(d0, off, 64);
        d1 += __shfl_xor(d1, off, 64);
        d2 += __shfl_xor(d2, off, 64);
        d3 += __shfl_xor(d3, off, 64);
    }
    d0 += e0; d1 += e1; d2 += e2; d3 += e3;
    const float i0 = 0.25f * __builtin_amdgcn_rcpf(d0);
    const float i1 = 0.25f * __builtin_amdgcn_rcpf(d1);
    const float i2 = 0.25f * __builtin_amdgcn_rcpf(d2);
    const float i3 = 0.25f * __builtin_amdgcn_rcpf(d3);

    if (lane < cn) {
        h2 wa; wa[0] = (f16)(w0 * i0); wa[1] = (f16)(w1 * i1);
        h2 wb; wb[0] = (f16)(w2 * i2); wb[1] = (f16)(w3 * i3);
        sh_w[wid][lane][0] = __builtin_bit_cast(unsigned, wa);
        sh_w[wid][lane][1] = __builtin_bit_cast(unsigned, wb);
        sh_off[wid][lane] = s << 9;           // s * HC * sizeof(f16)
    } else if (lane == cn) {                   // self-loop as edge slot cn
        h2 wa; wa[0] = (f16)(e0 * i0); wa[1] = (f16)(e1 * i1);
        h2 wb; wb[0] = (f16)(e2 * i2); wb[1] = (f16)(e3 * i3);
        sh_w[wid][cn][0] = __builtin_bit_cast(unsigned, wa);
        sh_w[wid][cn][1] = __builtin_bit_cast(unsigned, wb);
        sh_off[wid][cn] = n << 9;
    }

    const int m = cn + 1;                      // entries incl. self
    const int half = lane >> 5, l32 = lane & 31;
    // lane owns channels (2*l32, 2*l32+1); half selects row within a pair
    const char* xb = (const char*)xl + l32 * 16;
    float acc0 = 0.f, acc1 = 0.f;

#define K3DOT(raw, wr) do {                                              \
        h2 va = bch2((raw).x), vb = bch2((raw).y);                       \
        h2 vc = bch2((raw).z), vd = bch2((raw).w);                       \
        h2 wa = bch2((wr).x),  wb = bch2((wr).y);                        \
        acc0 = dot2h(va, wa, acc0); acc0 = dot2h(vb, wb, acc0);          \
        acc1 = dot2h(vc, wa, acc1); acc1 = dot2h(vd, wb, acc1);          \
    } while (0)

    int j = 0;
    for (; j + 4 <= m; j += 4) {               // 2 pairs in flight
        int offA = sh_off[wid][j + half];
        int offB = sh_off[wid][j + 2 + half];
        uint4 ra = *(const uint4*)(xb + offA);
        uint4 rb = *(const uint4*)(xb + offB);
        uint2 wA = *(const uint2*)&sh_w[wid][j + half][0];
        uint2 wB = *(const uint2*)&sh_w[wid][j + 2 + half][0];
        K3DOT(ra, wA);
        K3DOT(rb, wB);
    }
    if (j + 2 <= m) {                          // one pair
        int offA = sh_off[wid][j + half];
        uint4 ra = *(const uint4*)(xb + offA);
        uint2 wA = *(const uint2*)&sh_w[wid][j + half][0];
        K3DOT(ra, wA);
        j += 2;
    }
    if (j < m && half == 0) {                  // odd tail: half0 only
        int offA = sh_off[wid][j];
        uint4 ra = *(const uint4*)(xb + offA);
        uint2 wA = *(const uint2*)&sh_w[wid][j][0];
        K3DOT(ra, wA);
    }
#undef K3DOT

    acc0 += __shfl_xor(acc0, 32, 64);
    acc1 += __shfl_xor(acc1, 32, 64);
    if (half == 0) {
        float2* p = (float2*)(out_acc + (size_t)n * CDIM + l32 * 2);
        float2 v = *p;
        v.x += acc0; v.y += acc1;
        *p = v;                                // seeded with residual + biases
    }
}

// ---------------------------------------------------------------------------
// K4: GraphNorm partial sums, atomic finish. Block covers 256 nodes;
//     waves accumulate per-graph partials in registers -> LDS -> one dense
//     atomicAdd pass into S1/S2 (pre-zeroed by kz; sorted batch -> ~2
//     graphs/block nonzero -> ~256 atomics on 1024 addrs). Block 0 also
//     computes start[] (binary search over sorted batch). Replaces k4+kr.
// ---------------------------------------------------------------------------
__global__ __launch_bounds__(256) void k4_stats(
        const float* __restrict__ out_acc, const int* __restrict__ batch,
        const int* __restrict__ ei,
        float* __restrict__ S1, float* __restrict__ S2,
        int* __restrict__ start, int N) {
    __shared__ float p1[4][BGRAPH][64], p2[4][BGRAPH][64];
    const int w = threadIdx.x >> 6;
    const int c = threadIdx.x & 63;
#pragma unroll
    for (int k = threadIdx.x; k < 4 * BGRAPH * 64; k += 256) {
        ((float*)p1)[k] = 0.f; ((float*)p2)[k] = 0.f;
    }
    __syncthreads();
    bool w64 = sniff_i64(ei);
    const int n0 = blockIdx.x * 256 + w * 64;
    float ls1 = 0.f, ls2 = 0.f;
    int curb = -1;
    for (int i = 0; i < 64; ++i) {
        int n = n0 + i;
        if (n >= N) break;
        float hv = out_acc[(size_t)n * CDIM + c];
        int b = gidx(batch, n, w64, BGRAPH);
        if (b != curb) {
            if (curb >= 0) { p1[w][curb][c] += ls1; p2[w][curb][c] += ls2; }
            curb = b; ls1 = 0.f; ls2 = 0.f;
        }
        ls1 += hv; ls2 += hv * hv;
    }
    if (curb >= 0) { p1[w][curb][c] += ls1; p2[w][curb][c] += ls2; }
    __syncthreads();
    for (int k = threadIdx.x; k < BGRAPH * 64; k += 256) {
        int b = k >> 6, cc = k & 63;
        float v1 = p1[0][b][cc] + p1[1][b][cc] + p1[2][b][cc] + p1[3][b][cc];
        float v2 = p2[0][b][cc] + p2[1][b][cc] + p2[2][b][cc] + p2[3][b][cc];
        if (v1 != 0.f) atomicAdd(&S1[k], v1);
        if (v2 != 0.f) atomicAdd(&S2[k], v2);
    }
    if (blockIdx.x == 0 && threadIdx.x <= BGRAPH) {
        int t = threadIdx.x;
        int lo = 0, hi = N;
        while (lo < hi) {
            int mid = (lo + hi) >> 1;
            long long bv = w64 ? ((const long long*)batch)[mid] : (long long)batch[mid];
            if (bv < t) lo = mid + 1; else hi = mid;
        }
        start[t] = lo;
    }
}

// ---------------------------------------------------------------------------
// K6: GraphNorm + GELU(tanh approx) -> out (dtype per sniff)
// ---------------------------------------------------------------------------
template <bool F32>
__device__ __forceinline__ void k6_impl(
        const float* __restrict__ out_acc, const int* __restrict__ batch,
        bool w64,
        const float* __restrict__ S1, const float* __restrict__ S2,
        const int* __restrict__ start, const void* __restrict__ gw,
        const void* __restrict__ gb, const void* __restrict__ msc,
        void* __restrict__ out, int N) {
    int idx = blockIdx.x * 256 + threadIdx.x;
    if (idx >= N * CDIM) return;
    int n = idx >> 6, c = idx & 63;
    int b = gidx(batch, n, w64, BGRAPH);
    int cnt_i = start[b + 1] - start[b];
    float cnt = (float)(cnt_i < 1 ? 1 : cnt_i);
    float m = S1[b * CDIM + c] / cnt;
    float ms = ldf<F32>(msc, c);
    float var = S2[b * CDIM + c] / cnt + m * m * ms * (ms - 2.0f);
    float centered = out_acc[idx] - m * ms;
    float normed = ldf<F32>(gw, c) * centered * rsqrtf(fmaxf(var, 0.f) + EPS_GN)
                   + ldf<F32>(gb, c);
    float t = 0.7978845608028654f * (normed + 0.044715f * normed * normed * normed);
    float gel = 0.5f * normed * (1.0f + tanhf(t));
    if constexpr (F32) ((float*)out)[idx] = gel;
    else               ((bf16*)out)[idx] = (bf16)gel;
}

__global__ __launch_bounds__(256) void k6_norm(
        const void* __restrict__ xsniff,
        const float* __restrict__ out_acc, const int* __restrict__ batch,
        const int* __restrict__ ei,
        const float* __restrict__ S1, const float* __restrict__ S2,
        const int* __restrict__ start, const void* __restrict__ gw,
        const void* __restrict__ gb, const void* __restrict__ msc,
        void* __restrict__ out, int N) {
    bool w64 = sniff_i64(ei);
    if (sniff_f32(xsniff))
        k6_impl<true >(out_acc, batch, w64, S1, S2, start, gw, gb, msc, out, N);
    else
        k6_impl<false>(out_acc, batch, w64, S1, S2, start, gw, gb, msc, out, N);
}

// ---------------------------------------------------------------------------
extern "C" void kernel_launch(void* const* d_in, const int* in_sizes, int n_in,
                              void* d_out, int out_size, void* d_ws, size_t ws_size,
                              hipStream_t stream) {
    const void* x     = d_in[0];
    const int*  ei    = (const int*)d_in[1];
    const int*  batch = (const int*)d_in[2];
    const void* W     = d_in[3];
    const void* attS  = d_in[4];
    const void* attD  = d_in[5];
    const void* biasG = d_in[6];
    const void* resW  = d_in[7];
    const void* resB  = d_in[8];
    const void* gw    = d_in[9];
    const void* gb    = d_in[10];
    const void* msc   = d_in[11];

    const int N = in_sizes[0] / FIN;
    const int E = in_sizes[1] / 2;
    const int NB = (N + 255) / 256;    // 256-node blocks (k4)
    const int NB1 = (N + 127) / 128;   // GEMM blocks in fused k1
    const int NBS = (E + 1023) / 1024; // scatter blocks in fused k1

    char* ws = (char*)d_ws;
    size_t off = 0;
    auto alloc = [&](size_t bytes) { char* p = ws + off; off = (off + bytes + 255) & ~(size_t)255; return p; };
    f16*   xl      = (f16*)  alloc((size_t)N * HC * sizeof(f16));
    float* out_acc = (float*)alloc((size_t)N * CDIM * sizeof(float));
    float* a_src   = (float*)alloc((size_t)N * HEADS * sizeof(float));
    float* a_dst   = (float*)alloc((size_t)N * HEADS * sizeof(float));
    int*   cnt     = (int*)  alloc((size_t)N * sizeof(int));
    float* S1      = (float*)alloc(BGRAPH * CDIM * sizeof(float));
    float* S2      = (float*)alloc(BGRAPH * CDIM * sizeof(float));
    int*   adj     = (int*)  alloc((size_t)N * CAP * sizeof(int));
    int*   start   = (int*)  alloc((BGRAPH + 1) * sizeof(int));

    hipLaunchKernelGGL(kz_zero, dim3((N + 255) / 256), dim3(256), 0, stream,
                       cnt, S1, S2, N);
    hipLaunchKernelGGL(k1_gemm, dim3(NB1 + NBS), dim3(256), 0, stream,
                       x, W, resW, resB, biasG, attS, attD, xl, out_acc,
                       a_src, a_dst, ei, cnt, adj, NB1, E, N);
    hipLaunchKernelGGL(k3_fused, dim3((N + 3) / 4), dim3(256), 0, stream,
                       cnt, adj, a_src, a_dst, xl, out_acc, N);
    hipLaunchKernelGGL(k4_stats, dim3(NB), dim3(256), 0, stream,
                       out_acc, batch, ei, S1, S2, start, N);
    hipLaunchKernelGGL(k6_norm, dim3((N * CDIM + 255) / 256), dim3(256), 0, stream,
                       x, out_acc, batch, ei, S1, S2, start, gw, gb, msc, d_out, N);
}

// Round 8
// 365.034 us; speedup vs baseline: 1.2685x; 1.0193x over previous
//
#include <hip/hip_runtime.h>
#include <hip/hip_bf16.h>

typedef __bf16 bf16;
typedef __bf16 bf16x4 __attribute__((ext_vector_type(4)));
typedef __bf16 bf16x8 __attribute__((ext_vector_type(8)));
typedef float floatx4 __attribute__((ext_vector_type(4)));
typedef _Float16 f16;
typedef _Float16 f16x4 __attribute__((ext_vector_type(4)));
typedef _Float16 h2 __attribute__((ext_vector_type(2)));

#define FIN 128
#define HC 256          // H*C
#define HEADS 4
#define CDIM 64
#define BGRAPH 8
#define NEG 0.2f
#define EPS_GN 1e-5f
#define CAP 48          // max in-degree slot capacity; P(Poisson(12)>48)~1e-13/node

// R19: k1's counters (occ 20%, VALU 5%, Mfma 2.6%, HBM 22% — all idle) showed
// it latency-bound at 2 waves/SIMD: the 64KB Wlds LDS capped BOTH the GEMM
// blocks and the fused scatter blocks (which never touch it) at 2 blocks/CU.
// Fix: W pre-converted to bf16 fragment order (Wbk1, 64KB) by kz blocks 0-15;
// GEMM reads fragments directly from global (coalesced 1KB/instr, L2-resident
// broadcast ~200MB ≈ 6us). k1 LDS 66.5KB -> 1KB; occupancy 8 -> 16 waves/CU.

__device__ __forceinline__ float lrelu(float v) { return v >= 0.f ? v : NEG * v; }
__device__ __forceinline__ float eexp(float v) { return __expf(fminf(v, 60.f)); }

__device__ __forceinline__ float dot2h(h2 a, h2 b, float c) {
#if __has_builtin(__builtin_amdgcn_fdot2)
    return __builtin_amdgcn_fdot2(a, b, c, false);
#else
    return c + (float)a[0] * (float)b[0] + (float)a[1] * (float)b[1];
#endif
}
__device__ __forceinline__ h2 bch2(unsigned u) { return __builtin_bit_cast(h2, u); }

// ---- runtime dtype sniffs (wave-uniform, decided from data) ----------------
__device__ __forceinline__ bool sniff_i64(const int* __restrict__ p) {
    bool w64 = true;
#pragma unroll
    for (int i = 1; i < 16; i += 2) w64 = w64 && (p[i] == 0);
    return w64;
}
__device__ __forceinline__ bool sniff_f32(const void* __restrict__ xv) {
    const unsigned* u = (const unsigned*)xv;
    bool bf = true;
#pragma unroll
    for (int i = 0; i < 8; ++i) {
        unsigned lo = u[i] & 0xFFFFu;
        unsigned ex = (lo >> 7) & 0xFFu;
        bf = bf && ((ex >= 96u && ex <= 129u) || lo == 0u);
    }
    return !bf;   // true => data is fp32
}

__device__ __forceinline__ int gidx(const int* __restrict__ p, long long i,
                                    bool w64, int hi) {
    long long v = w64 ? ((const long long*)p)[i] : (long long)p[i];
    int x = (int)v;
    return x < 0 ? 0 : (x >= hi ? hi - 1 : x);
}

template <bool F32>
__device__ __forceinline__ float ldf(const void* __restrict__ p, int i) {
    if constexpr (F32) return ((const float*)p)[i];
    else               return (float)((const bf16*)p)[i];
}

template <bool F32>
__device__ __forceinline__ bf16x8 load8(const void* __restrict__ base, size_t off) {
    if constexpr (F32) {
        const float* p = (const float*)base + off;
        float4 a = *(const float4*)p, b = *(const float4*)(p + 4);
        bf16x8 r;
        r[0] = (bf16)a.x; r[1] = (bf16)a.y; r[2] = (bf16)a.z; r[3] = (bf16)a.w;
        r[4] = (bf16)b.x; r[5] = (bf16)b.y; r[6] = (bf16)b.z; r[7] = (bf16)b.w;
        return r;
    } else {
        return *(const bf16x8*)((const bf16*)base + off);
    }
}

// ---------------------------------------------------------------------------
// KZ: zero cnt[N] + S1 + S2; blocks 0-15 also convert W -> Wbk1 (bf16,
//     k1 fragment order: entry i={tileq=i>>6,lane=i&63}).
// ---------------------------------------------------------------------------
__global__ __launch_bounds__(256) void kz_zero(
        int* __restrict__ cnt, float* __restrict__ S1,
        float* __restrict__ S2, const void* __restrict__ W,
        bf16* __restrict__ Wbk1, int N) {
    int i = blockIdx.x * 256 + threadIdx.x;
    if (i < N) cnt[i] = 0;
    if (i < BGRAPH * CDIM) { S1[i] = 0.f; S2[i] = 0.f; }
    if (i < 4096) {
        const bool f32 = sniff_f32(W);
        int tileq = i >> 6, lane = i & 63;
        int tile = tileq >> 2, kq = tileq & 3;
        int R = tile * 16 + (lane & 15);
        size_t off = (size_t)((R & 3) * 64 + (R >> 2)) * FIN + kq * 32 + (lane >> 4) * 8;
        bf16x8 v = f32 ? load8<true>(W, off) : load8<false>(W, off);
        *(bf16x8*)(Wbk1 + (size_t)i * 8) = v;
    }
}

// ---------------------------------------------------------------------------
// K1 (fused with kscat): first NB1 blocks do the transposed fused GEMM
//     (f16 xl, att partials, residual epilogue), W fragments from global
//     Wbk1; remaining blocks scatter edges into capacity-CSR.
// ---------------------------------------------------------------------------
template <bool F32>
__device__ __forceinline__ void k1_impl(
        const void* __restrict__ x, const bf16x8* __restrict__ Wb,
        const void* __restrict__ resW, const void* __restrict__ resB,
        const void* __restrict__ biasG,
        const bf16* __restrict__ aSc, const bf16* __restrict__ aDc,
        f16* __restrict__ xl, float* __restrict__ out_acc,
        float* __restrict__ a_src, float* __restrict__ a_dst, int N) {
    const int wave = threadIdx.x >> 6;
    const int lane = threadIdx.x & 63;
    const int nl = lane & 15;          // node within tile / D-col
    const int q  = lane >> 4;          // K-quad; D rows q*4..q*4+3
    const int base = blockIdx.x * 128 + wave * 32;

    bf16x8 xf[2][4];
    int nodes[2]; bool g[2];
#pragma unroll
    for (int nt = 0; nt < 2; ++nt) {
        int node = base + nt * 16 + nl;
        nodes[nt] = node; g[nt] = node < N;
        int cn = g[nt] ? node : N - 1;
#pragma unroll
        for (int kq = 0; kq < 4; ++kq)
            xf[nt][kq] = load8<F32>(x, (size_t)cn * FIN + kq * 32 + q * 8);
    }

    float s[2][4] = {{0,0,0,0},{0,0,0,0}};
    float d[2][4] = {{0,0,0,0},{0,0,0,0}};

#pragma unroll
    for (int tile = 0; tile < 16; ++tile) {
        bf16x8 wf[4];
#pragma unroll
        for (int kq = 0; kq < 4; ++kq)
            wf[kq] = Wb[(tile * 4 + kq) * 64 + lane];   // global, coalesced, L2-hot
        const int e0 = tile * 16 + q * 4;   // e = e0 + r ; head h = e&3 = r
        bf16x4 sa = *(const bf16x4*)(aSc + e0);
        bf16x4 da = *(const bf16x4*)(aDc + e0);
#pragma unroll
        for (int nt = 0; nt < 2; ++nt) {
            floatx4 acc = {0,0,0,0};
#pragma unroll
            for (int kq = 0; kq < 4; ++kq)
                acc = __builtin_amdgcn_mfma_f32_16x16x32_bf16(wf[kq], xf[nt][kq], acc, 0, 0, 0);
            f16x4 p;
#pragma unroll
            for (int r = 0; r < 4; ++r) {
                p[r] = (f16)acc[r];
                s[nt][r] += acc[r] * (float)sa[r];
                d[nt][r] += acc[r] * (float)da[r];
            }
            if (g[nt]) *(f16x4*)(xl + (size_t)nodes[nt] * HC + e0) = p;
        }
    }

    // ---- residual tiles (4 x 16 output channels), resW direct global ----
#pragma unroll
    for (int tile = 0; tile < 4; ++tile) {
        const int R = tile * 16 + nl;
        bf16x8 wf[4];
#pragma unroll
        for (int kq = 0; kq < 4; ++kq)
            wf[kq] = load8<F32>(resW, (size_t)R * FIN + kq * 32 + q * 8);
        const int c0 = tile * 16 + q * 4;
        const float b0 = ldf<F32>(resB, c0 + 0) + ldf<F32>(biasG, c0 + 0);
        const float b1 = ldf<F32>(resB, c0 + 1) + ldf<F32>(biasG, c0 + 1);
        const float b2 = ldf<F32>(resB, c0 + 2) + ldf<F32>(biasG, c0 + 2);
        const float b3 = ldf<F32>(resB, c0 + 3) + ldf<F32>(biasG, c0 + 3);
#pragma unroll
        for (int nt = 0; nt < 2; ++nt) {
            floatx4 acc = {0,0,0,0};
#pragma unroll
            for (int kq = 0; kq < 4; ++kq)
                acc = __builtin_amdgcn_mfma_f32_16x16x32_bf16(wf[kq], xf[nt][kq], acc, 0, 0, 0);
            float4 v = make_float4(acc[0] + b0, acc[1] + b1, acc[2] + b2, acc[3] + b3);
            if (g[nt]) *(float4*)(out_acc + (size_t)nodes[nt] * CDIM + c0) = v;
        }
    }

    // ---- reduce att partials across the 4 q-lanes, store from q==0 ----
#pragma unroll
    for (int off = 16; off <= 32; off <<= 1) {
#pragma unroll
        for (int nt = 0; nt < 2; ++nt)
#pragma unroll
            for (int r = 0; r < 4; ++r) {
                s[nt][r] += __shfl_xor(s[nt][r], off, 64);
                d[nt][r] += __shfl_xor(d[nt][r], off, 64);
            }
    }
    if (q == 0) {
#pragma unroll
        for (int nt = 0; nt < 2; ++nt) {
            if (g[nt]) {
                *(float4*)(a_src + (size_t)nodes[nt] * 4) =
                    make_float4(s[nt][0], s[nt][1], s[nt][2], s[nt][3]);
                *(float4*)(a_dst + (size_t)nodes[nt] * 4) =
                    make_float4(d[nt][0], d[nt][1], d[nt][2], d[nt][3]);
            }
        }
    }
}

__global__ __launch_bounds__(256, 2) void k1_gemm(
        const void* __restrict__ x, const bf16* __restrict__ Wbk1,
        const void* __restrict__ resW, const void* __restrict__ resB,
        const void* __restrict__ biasG, const void* __restrict__ attS,
        const void* __restrict__ attD,
        f16* __restrict__ xl, float* __restrict__ out_acc,
        float* __restrict__ a_src, float* __restrict__ a_dst,
        const int* __restrict__ ei, int* __restrict__ cnt,
        int* __restrict__ adj, int NB1, int E, int N) {
    __shared__ bf16 aSc[HC], aDc[HC];   // 1 KB total — no more 64KB W LDS
    const int t = threadIdx.x;

    if (blockIdx.x >= NB1) {
        // ---- scatter blocks: capacity-CSR build, 4 edges/thread ----
        const long long base = (long long)(blockIdx.x - NB1) * 1024;
        const bool w64 = sniff_i64(ei);
#pragma unroll
        for (int u = 0; u < 4; ++u) {
            long long e = base + u * 256 + t;
            if (e < E) {
                int s = gidx(ei, e, w64, N);
                int d = gidx(ei, (long long)E + e, w64, N);
                int pos = atomicAdd(&cnt[d], 1);
                if (pos < CAP) adj[(size_t)d * CAP + pos] = s;
            }
        }
        return;
    }

    const bool f32 = sniff_f32(x);
    {   // stage att channel-major: aSc[e] = attS[(e&3)*64 + (e>>2)]
        int src = (t & 3) * 64 + (t >> 2);
        aSc[t] = f32 ? (bf16)((const float*)attS)[src] : ((const bf16*)attS)[src];
        aDc[t] = f32 ? (bf16)((const float*)attD)[src] : ((const bf16*)attD)[src];
    }
    __syncthreads();
    if (f32) k1_impl<true >(x, (const bf16x8*)Wbk1, resW, resB, biasG, aSc, aDc, xl, out_acc, a_src, a_dst, N);
    else     k1_impl<false>(x, (const bf16x8*)Wbk1, resW, resB, biasG, aSc, aDc, xl, out_acc, a_src, a_dst, N);
}

// ---------------------------------------------------------------------------
// K3: fused softmax + aggregation over capacity-CSR. One wave per node.
//     R13-proven kernel: f16 xl + fdot2, half-wave dwordx4 row loads,
//     pre-normalized f16 weights, self-loop as edge slot cn. 107us, occ 80%.
// ---------------------------------------------------------------------------
__global__ __launch_bounds__(256) void k3_fused(
        const int* __restrict__ cnt, const int* __restrict__ adj,
        const float* __restrict__ a_src, const float* __restrict__ a_dst,
        const f16* __restrict__ xl, float* __restrict__ out_acc, int N) {
    __shared__ unsigned sh_w[4][64][2];   // normalized f16x4 weights per entry
    __shared__ int      sh_off[4][64];    // row byte offsets (s*512)
    const int wid  = threadIdx.x >> 6;
    const int lane = threadIdx.x & 63;
    const int n = blockIdx.x * 4 + wid;
    if (n >= N) return;
    int cn = cnt[n]; if (cn > CAP) cn = CAP;
    const float4 ad  = *(const float4*)(a_dst + (size_t)n * 4);
    const float4 asn = *(const float4*)(a_src + (size_t)n * 4);
    const float e0 = eexp(lrelu(asn.x + ad.x));
    const float e1 = eexp(lrelu(asn.y + ad.y));
    const float e2 = eexp(lrelu(asn.z + ad.z));
    const float e3 = eexp(lrelu(asn.w + ad.w));

    float w0 = 0.f, w1 = 0.f, w2 = 0.f, w3 = 0.f;
    float d0 = 0.f, d1 = 0.f, d2 = 0.f, d3 = 0.f;
    int s = 0;
    if (lane < cn) {
        s = adj[(size_t)n * CAP + lane];
        float4 as = *(const float4*)(a_src + (size_t)s * 4);
        w0 = eexp(lrelu(as.x + ad.x));
        w1 = eexp(lrelu(as.y + ad.y));
        w2 = eexp(lrelu(as.z + ad.z));
        w3 = eexp(lrelu(as.w + ad.w));
        d0 = w0; d1 = w1; d2 = w2; d3 = w3;
    }
    // wave-reduce denominators, add self, fold 0.25 head-mean into inverse
#pragma unroll
    for (int off = 1; off <= 32; off <<= 1) {
        d0 += __shfl_xor(d0, off, 64);
        d1 += __shfl_xor(d1, off, 64);
        d2 += __shfl_xor(d2, off, 64);
        d3 += __shfl_xor(d3, off, 64);
    }
    d0 += e0; d1 += e1; d2 += e2; d3 += e3;
    const float i0 = 0.25f * __builtin_amdgcn_rcpf(d0);
    const float i1 = 0.25f * __builtin_amdgcn_rcpf(d1);
    const float i2 = 0.25f * __builtin_amdgcn_rcpf(d2);
    const float i3 = 0.25f * __builtin_amdgcn_rcpf(d3);

    if (lane < cn) {
        h2 wa; wa[0] = (f16)(w0 * i0); wa[1] = (f16)(w1 * i1);
        h2 wb; wb[0] = (f16)(w2 * i2); wb[1] = (f16)(w3 * i3);
        sh_w[wid][lane][0] = __builtin_bit_cast(unsigned, wa);
        sh_w[wid][lane][1] = __builtin_bit_cast(unsigned, wb);
        sh_off[wid][lane] = s << 9;           // s * HC * sizeof(f16)
    } else if (lane == cn) {                   // self-loop as edge slot cn
        h2 wa; wa[0] = (f16)(e0 * i0); wa[1] = (f16)(e1 * i1);
        h2 wb; wb[0] = (f16)(e2 * i2); wb[1] = (f16)(e3 * i3);
        sh_w[wid][cn][0] = __builtin_bit_cast(unsigned, wa);
        sh_w[wid][cn][1] = __builtin_bit_cast(unsigned, wb);
        sh_off[wid][cn] = n << 9;
    }

    const int m = cn + 1;                      // entries incl. self
    const int half = lane >> 5, l32 = lane & 31;
    // lane owns channels (2*l32, 2*l32+1); half selects row within a pair
    const char* xb = (const char*)xl + l32 * 16;
    float acc0 = 0.f, acc1 = 0.f;

#define K3DOT(raw, wr) do {                                              \
        h2 va = bch2((raw).x), vb = bch2((raw).y);                       \
        h2 vc = bch2((raw).z), vd = bch2((raw).w);                       \
        h2 wa = bch2((wr).x),  wb = bch2((wr).y);                        \
        acc0 = dot2h(va, wa, acc0); acc0 = dot2h(vb, wb, acc0);          \
        acc1 = dot2h(vc, wa, acc1); acc1 = dot2h(vd, wb, acc1);          \
    } while (0)

    int j = 0;
    for (; j + 4 <= m; j += 4) {               // 2 pairs in flight
        int offA = sh_off[wid][j + half];
        int offB = sh_off[wid][j + 2 + half];
        uint4 ra = *(const uint4*)(xb + offA);
        uint4 rb = *(const uint4*)(xb + offB);
        uint2 wA = *(const uint2*)&sh_w[wid][j + half][0];
        uint2 wB = *(const uint2*)&sh_w[wid][j + 2 + half][0];
        K3DOT(ra, wA);
        K3DOT(rb, wB);
    }
    if (j + 2 <= m) {                          // one pair
        int offA = sh_off[wid][j + half];
        uint4 ra = *(const uint4*)(xb + offA);
        uint2 wA = *(const uint2*)&sh_w[wid][j + half][0];
        K3DOT(ra, wA);
        j += 2;
    }
    if (j < m && half == 0) {                  // odd tail: half0 only
        int offA = sh_off[wid][j];
        uint4 ra = *(const uint4*)(xb + offA);
        uint2 wA = *(const uint2*)&sh_w[wid][j][0];
        K3DOT(ra, wA);
    }
#undef K3DOT

    acc0 += __shfl_xor(acc0, 32, 64);
    acc1 += __shfl_xor(acc1, 32, 64);
    if (half == 0) {
        float2* p = (float2*)(out_acc + (size_t)n * CDIM + l32 * 2);
        float2 v = *p;
        v.x += acc0; v.y += acc1;
        *p = v;                                // seeded with residual + biases
    }
}

// ---------------------------------------------------------------------------
// K4: GraphNorm partial sums, atomic finish; block 0 computes start[].
// ---------------------------------------------------------------------------
__global__ __launch_bounds__(256) void k4_stats(
        const float* __restrict__ out_acc, const int* __restrict__ batch,
        const int* __restrict__ ei,
        float* __restrict__ S1, float* __restrict__ S2,
        int* __restrict__ start, int N) {
    __shared__ float p1[4][BGRAPH][64], p2[4][BGRAPH][64];
    const int w = threadIdx.x >> 6;
    const int c = threadIdx.x & 63;
#pragma unroll
    for (int k = threadIdx.x; k < 4 * BGRAPH * 64; k += 256) {
        ((float*)p1)[k] = 0.f; ((float*)p2)[k] = 0.f;
    }
    __syncthreads();
    bool w64 = sniff_i64(ei);
    const int n0 = blockIdx.x * 256 + w * 64;
    float ls1 = 0.f, ls2 = 0.f;
    int curb = -1;
    for (int i = 0; i < 64; ++i) {
        int n = n0 + i;
        if (n >= N) break;
        float hv = out_acc[(size_t)n * CDIM + c];
        int b = gidx(batch, n, w64, BGRAPH);
        if (b != curb) {
            if (curb >= 0) { p1[w][curb][c] += ls1; p2[w][curb][c] += ls2; }
            curb = b; ls1 = 0.f; ls2 = 0.f;
        }
        ls1 += hv; ls2 += hv * hv;
    }
    if (curb >= 0) { p1[w][curb][c] += ls1; p2[w][curb][c] += ls2; }
    __syncthreads();
    for (int k = threadIdx.x; k < BGRAPH * 64; k += 256) {
        int b = k >> 6, cc = k & 63;
        float v1 = p1[0][b][cc] + p1[1][b][cc] + p1[2][b][cc] + p1[3][b][cc];
        float v2 = p2[0][b][cc] + p2[1][b][cc] + p2[2][b][cc] + p2[3][b][cc];
        if (v1 != 0.f) atomicAdd(&S1[k], v1);
        if (v2 != 0.f) atomicAdd(&S2[k], v2);
    }
    if (blockIdx.x == 0 && threadIdx.x <= BGRAPH) {
        int t = threadIdx.x;
        int lo = 0, hi = N;
        while (lo < hi) {
            int mid = (lo + hi) >> 1;
            long long bv = w64 ? ((const long long*)batch)[mid] : (long long)batch[mid];
            if (bv < t) lo = mid + 1; else hi = mid;
        }
        start[t] = lo;
    }
}

// ---------------------------------------------------------------------------
// K6: GraphNorm + GELU(tanh approx) -> out (dtype per sniff)
// ---------------------------------------------------------------------------
template <bool F32>
__device__ __forceinline__ void k6_impl(
        const float* __restrict__ out_acc, const int* __restrict__ batch,
        bool w64,
        const float* __restrict__ S1, const float* __restrict__ S2,
        const int* __restrict__ start, const void* __restrict__ gw,
        const void* __restrict__ gb, const void* __restrict__ msc,
        void* __restrict__ out, int N) {
    int idx = blockIdx.x * 256 + threadIdx.x;
    if (idx >= N * CDIM) return;
    int n = idx >> 6, c = idx & 63;
    int b = gidx(batch, n, w64, BGRAPH);
    int cnt_i = start[b + 1] - start[b];
    float cnt = (float)(cnt_i < 1 ? 1 : cnt_i);
    float m = S1[b * CDIM + c] / cnt;
    float ms = ldf<F32>(msc, c);
    float var = S2[b * CDIM + c] / cnt + m * m * ms * (ms - 2.0f);
    float centered = out_acc[idx] - m * ms;
    float normed = ldf<F32>(gw, c) * centered * rsqrtf(fmaxf(var, 0.f) + EPS_GN)
                   + ldf<F32>(gb, c);
    float t = 0.7978845608028654f * (normed + 0.044715f * normed * normed * normed);
    float gel = 0.5f * normed * (1.0f + tanhf(t));
    if constexpr (F32) ((float*)out)[idx] = gel;
    else               ((bf16*)out)[idx] = (bf16)gel;
}

__global__ __launch_bounds__(256) void k6_norm(
        const void* __restrict__ xsniff,
        const float* __restrict__ out_acc, const int* __restrict__ batch,
        const int* __restrict__ ei,
        const float* __restrict__ S1, const float* __restrict__ S2,
        const int* __restrict__ start, const void* __restrict__ gw,
        const void* __restrict__ gb, const void* __restrict__ msc,
        void* __restrict__ out, int N) {
    bool w64 = sniff_i64(ei);
    if (sniff_f32(xsniff))
        k6_impl<true >(out_acc, batch, w64, S1, S2, start, gw, gb, msc, out, N);
    else
        k6_impl<false>(out_acc, batch, w64, S1, S2, start, gw, gb, msc, out, N);
}

// ---------------------------------------------------------------------------
extern "C" void kernel_launch(void* const* d_in, const int* in_sizes, int n_in,
                              void* d_out, int out_size, void* d_ws, size_t ws_size,
                              hipStream_t stream) {
    const void* x     = d_in[0];
    const int*  ei    = (const int*)d_in[1];
    const int*  batch = (const int*)d_in[2];
    const void* W     = d_in[3];
    const void* attS  = d_in[4];
    const void* attD  = d_in[5];
    const void* biasG = d_in[6];
    const void* resW  = d_in[7];
    const void* resB  = d_in[8];
    const void* gw    = d_in[9];
    const void* gb    = d_in[10];
    const void* msc   = d_in[11];

    const int N = in_sizes[0] / FIN;
    const int E = in_sizes[1] / 2;
    const int NB = (N + 255) / 256;    // 256-node blocks (k4)
    const int NB1 = (N + 127) / 128;   // GEMM blocks in fused k1
    const int NBS = (E + 1023) / 1024; // scatter blocks in fused k1

    char* ws = (char*)d_ws;
    size_t off = 0;
    auto alloc = [&](size_t bytes) { char* p = ws + off; off = (off + bytes + 255) & ~(size_t)255; return p; };
    f16*   xl      = (f16*)  alloc((size_t)N * HC * sizeof(f16));
    float* out_acc = (float*)alloc((size_t)N * CDIM * sizeof(float));
    float* a_src   = (float*)alloc((size_t)N * HEADS * sizeof(float));
    float* a_dst   = (float*)alloc((size_t)N * HEADS * sizeof(float));
    int*   cnt     = (int*)  alloc((size_t)N * sizeof(int));
    float* S1      = (float*)alloc(BGRAPH * CDIM * sizeof(float));
    float* S2      = (float*)alloc(BGRAPH * CDIM * sizeof(float));
    int*   adj     = (int*)  alloc((size_t)N * CAP * sizeof(int));
    bf16*  Wbk1    = (bf16*) alloc((size_t)HC * FIN * sizeof(bf16));   // 64 KB
    int*   start   = (int*)  alloc((BGRAPH + 1) * sizeof(int));

    hipLaunchKernelGGL(kz_zero, dim3((N + 255) / 256), dim3(256), 0, stream,
                       cnt, S1, S2, W, Wbk1, N);
    hipLaunchKernelGGL(k1_gemm, dim3(NB1 + NBS), dim3(256), 0, stream,
                       x, Wbk1, resW, resB, biasG, attS, attD, xl, out_acc,
                       a_src, a_dst, ei, cnt, adj, NB1, E, N);
    hipLaunchKernelGGL(k3_fused, dim3((N + 3) / 4), dim3(256), 0, stream,
                       cnt, adj, a_src, a_dst, xl, out_acc, N);
    hipLaunchKernelGGL(k4_stats, dim3(NB), dim3(256), 0, stream,
                       out_acc, batch, ei, S1, S2, start, N);
    hipLaunchKernelGGL(k6_norm, dim3((N * CDIM + 255) / 256), dim3(256), 0, stream,
                       x, out_acc, batch, ei, S1, S2, start, gw, gb, msc, d_out, N);
}

// Round 9
// 362.405 us; speedup vs baseline: 1.2778x; 1.0073x over previous
//
#include <hip/hip_runtime.h>
#include <hip/hip_bf16.h>

typedef __bf16 bf16;
typedef __bf16 bf16x4 __attribute__((ext_vector_type(4)));
typedef __bf16 bf16x8 __attribute__((ext_vector_type(8)));
typedef float floatx4 __attribute__((ext_vector_type(4)));
typedef _Float16 f16;
typedef _Float16 f16x4 __attribute__((ext_vector_type(4)));
typedef _Float16 h2 __attribute__((ext_vector_type(2)));

#define FIN 128
#define HC 256          // H*C
#define HEADS 4
#define CDIM 64
#define BGRAPH 8
#define NEG 0.2f
#define EPS_GN 1e-5f
#define CAP 48          // max in-degree slot capacity; P(Poisson(12)>48)~1e-13/node

// R20: k1 WRITE_SIZE was 182MB vs ~80MB logical -> partial-line RFO from
// 8B/lane scattered xl stores (16 lines/instr), scattered out_acc float4,
// and 4B random adj writes (77MB of pulled lines). Fix: stage xl (64KB) and
// out_acc (32KB, reused LDS) per block, flush with fully-coalesced 16B/lane
// contiguous stores; adj via nontemporal store. LDS 65KB = 2 blocks/CU,
// which R7<->R8 A/B proved perf-neutral for this kernel (occ-invariant).

__device__ __forceinline__ float lrelu(float v) { return v >= 0.f ? v : NEG * v; }
__device__ __forceinline__ float eexp(float v) { return __expf(fminf(v, 60.f)); }

__device__ __forceinline__ float dot2h(h2 a, h2 b, float c) {
#if __has_builtin(__builtin_amdgcn_fdot2)
    return __builtin_amdgcn_fdot2(a, b, c, false);
#else
    return c + (float)a[0] * (float)b[0] + (float)a[1] * (float)b[1];
#endif
}
__device__ __forceinline__ h2 bch2(unsigned u) { return __builtin_bit_cast(h2, u); }

// ---- runtime dtype sniffs (wave-uniform, decided from data) ----------------
__device__ __forceinline__ bool sniff_i64(const int* __restrict__ p) {
    bool w64 = true;
#pragma unroll
    for (int i = 1; i < 16; i += 2) w64 = w64 && (p[i] == 0);
    return w64;
}
__device__ __forceinline__ bool sniff_f32(const void* __restrict__ xv) {
    const unsigned* u = (const unsigned*)xv;
    bool bf = true;
#pragma unroll
    for (int i = 0; i < 8; ++i) {
        unsigned lo = u[i] & 0xFFFFu;
        unsigned ex = (lo >> 7) & 0xFFu;
        bf = bf && ((ex >= 96u && ex <= 129u) || lo == 0u);
    }
    return !bf;   // true => data is fp32
}

__device__ __forceinline__ int gidx(const int* __restrict__ p, long long i,
                                    bool w64, int hi) {
    long long v = w64 ? ((const long long*)p)[i] : (long long)p[i];
    int x = (int)v;
    return x < 0 ? 0 : (x >= hi ? hi - 1 : x);
}

template <bool F32>
__device__ __forceinline__ float ldf(const void* __restrict__ p, int i) {
    if constexpr (F32) return ((const float*)p)[i];
    else               return (float)((const bf16*)p)[i];
}

template <bool F32>
__device__ __forceinline__ bf16x8 load8(const void* __restrict__ base, size_t off) {
    if constexpr (F32) {
        const float* p = (const float*)base + off;
        float4 a = *(const float4*)p, b = *(const float4*)(p + 4);
        bf16x8 r;
        r[0] = (bf16)a.x; r[1] = (bf16)a.y; r[2] = (bf16)a.z; r[3] = (bf16)a.w;
        r[4] = (bf16)b.x; r[5] = (bf16)b.y; r[6] = (bf16)b.z; r[7] = (bf16)b.w;
        return r;
    } else {
        return *(const bf16x8*)((const bf16*)base + off);
    }
}

// ---------------------------------------------------------------------------
// KZ: zero cnt[N] + S1 + S2; blocks 0-15 also convert W -> Wbk1 (bf16,
//     k1 fragment order: entry i={tileq=i>>6,lane=i&63}).
// ---------------------------------------------------------------------------
__global__ __launch_bounds__(256) void kz_zero(
        int* __restrict__ cnt, float* __restrict__ S1,
        float* __restrict__ S2, const void* __restrict__ W,
        bf16* __restrict__ Wbk1, int N) {
    int i = blockIdx.x * 256 + threadIdx.x;
    if (i < N) cnt[i] = 0;
    if (i < BGRAPH * CDIM) { S1[i] = 0.f; S2[i] = 0.f; }
    if (i < 4096) {
        const bool f32 = sniff_f32(W);
        int tileq = i >> 6, lane = i & 63;
        int tile = tileq >> 2, kq = tileq & 3;
        int R = tile * 16 + (lane & 15);
        size_t off = (size_t)((R & 3) * 64 + (R >> 2)) * FIN + kq * 32 + (lane >> 4) * 8;
        bf16x8 v = f32 ? load8<true>(W, off) : load8<false>(W, off);
        *(bf16x8*)(Wbk1 + (size_t)i * 8) = v;
    }
}

// ---------------------------------------------------------------------------
// K1 (fused with kscat): first NB1 blocks do the transposed fused GEMM
//     (W fragments from global Wbk1, L2-hot); xl and out_acc staged in LDS
//     and flushed with coalesced 16B/lane stores. Remaining blocks scatter
//     edges into capacity-CSR with nontemporal adj stores.
// ---------------------------------------------------------------------------
template <bool F32>
__device__ __forceinline__ void k1_impl(
        const void* __restrict__ x, const bf16x8* __restrict__ Wb,
        const void* __restrict__ resW, const void* __restrict__ resB,
        const void* __restrict__ biasG,
        const bf16* __restrict__ aSc, const bf16* __restrict__ aDc,
        char* __restrict__ lds,
        f16* __restrict__ xl, float* __restrict__ out_acc,
        float* __restrict__ a_src, float* __restrict__ a_dst, int N) {
    const int wave = threadIdx.x >> 6;
    const int lane = threadIdx.x & 63;
    const int nl = lane & 15;          // node within tile / D-col
    const int q  = lane >> 4;          // K-quad; D rows q*4..q*4+3
    const int base = blockIdx.x * 128 + wave * 32;
    const int gbase = blockIdx.x * 128;

    bf16x8 xf[2][4];
    int nodes[2]; bool g[2];
#pragma unroll
    for (int nt = 0; nt < 2; ++nt) {
        int node = base + nt * 16 + nl;
        nodes[nt] = node; g[nt] = node < N;
        int cn = g[nt] ? node : N - 1;
#pragma unroll
        for (int kq = 0; kq < 4; ++kq)
            xf[nt][kq] = load8<F32>(x, (size_t)cn * FIN + kq * 32 + q * 8);
    }

    float s[2][4] = {{0,0,0,0},{0,0,0,0}};
    float d[2][4] = {{0,0,0,0},{0,0,0,0}};

#pragma unroll
    for (int tile = 0; tile < 16; ++tile) {
        bf16x8 wf[4];
#pragma unroll
        for (int kq = 0; kq < 4; ++kq)
            wf[kq] = Wb[(tile * 4 + kq) * 64 + lane];   // global, coalesced, L2-hot
        const int e0 = tile * 16 + q * 4;   // e = e0 + r ; head h = e&3 = r
        bf16x4 sa = *(const bf16x4*)(aSc + e0);
        bf16x4 da = *(const bf16x4*)(aDc + e0);
#pragma unroll
        for (int nt = 0; nt < 2; ++nt) {
            floatx4 acc = {0,0,0,0};
#pragma unroll
            for (int kq = 0; kq < 4; ++kq)
                acc = __builtin_amdgcn_mfma_f32_16x16x32_bf16(wf[kq], xf[nt][kq], acc, 0, 0, 0);
            f16x4 p;
#pragma unroll
            for (int r = 0; r < 4; ++r) {
                p[r] = (f16)acc[r];
                s[nt][r] += acc[r] * (float)sa[r];
                d[nt][r] += acc[r] * (float)da[r];
            }
            {   // stage to LDS (swizzled); flushed coalesced below
                unsigned node_l = (unsigned)(wave * 32 + nt * 16 + nl);
                unsigned off = (unsigned)(tile * 32 + q * 8);
                *(f16x4*)(lds + node_l * 512 + (off ^ ((node_l & 7u) << 4))) = p;
            }
        }
    }

    // ---- flush xl: 64KB, fully coalesced 16B/thread x16 iters ----
    __syncthreads();
    {
        const int t = threadIdx.x;
#pragma unroll
        for (int it = 0; it < 16; ++it) {
            int idx = it * 4096 + t * 16;
            int nloc = idx >> 9;            // /512
            int r = idx & 511;
            int gn = gbase + nloc;
            if (gn < N) {
                uint4 v = *(const uint4*)(lds + nloc * 512 + (r ^ ((nloc & 7) << 4)));
                *(uint4*)((char*)xl + (size_t)gn * 512 + r) = v;
            }
        }
    }
    __syncthreads();   // before reusing lds for out_acc staging

    // ---- residual tiles (4 x 16 output channels), resW direct global ----
#pragma unroll
    for (int tile = 0; tile < 4; ++tile) {
        const int R = tile * 16 + nl;
        bf16x8 wf[4];
#pragma unroll
        for (int kq = 0; kq < 4; ++kq)
            wf[kq] = load8<F32>(resW, (size_t)R * FIN + kq * 32 + q * 8);
        const int c0 = tile * 16 + q * 4;
        const float b0 = ldf<F32>(resB, c0 + 0) + ldf<F32>(biasG, c0 + 0);
        const float b1 = ldf<F32>(resB, c0 + 1) + ldf<F32>(biasG, c0 + 1);
        const float b2 = ldf<F32>(resB, c0 + 2) + ldf<F32>(biasG, c0 + 2);
        const float b3 = ldf<F32>(resB, c0 + 3) + ldf<F32>(biasG, c0 + 3);
#pragma unroll
        for (int nt = 0; nt < 2; ++nt) {
            floatx4 acc = {0,0,0,0};
#pragma unroll
            for (int kq = 0; kq < 4; ++kq)
                acc = __builtin_amdgcn_mfma_f32_16x16x32_bf16(wf[kq], xf[nt][kq], acc, 0, 0, 0);
            float4 v = make_float4(acc[0] + b0, acc[1] + b1, acc[2] + b2, acc[3] + b3);
            {   // stage to LDS (reuse, 32KB region)
                unsigned node_l = (unsigned)(wave * 32 + nt * 16 + nl);
                unsigned off = (unsigned)(tile * 64 + q * 16);
                *(float4*)(lds + node_l * 256 + (off ^ ((node_l & 7u) << 4))) = v;
            }
        }
    }

    // ---- flush out_acc: 32KB, coalesced 16B/thread x8 iters ----
    __syncthreads();
    {
        const int t = threadIdx.x;
#pragma unroll
        for (int it = 0; it < 8; ++it) {
            int idx = it * 4096 + t * 16;
            int nloc = idx >> 8;            // /256
            int r = idx & 255;
            int gn = gbase + nloc;
            if (gn < N) {
                float4 v = *(const float4*)(lds + nloc * 256 + (r ^ ((nloc & 7) << 4)));
                *(float4*)((char*)out_acc + (size_t)gn * 256 + r) = v;
            }
        }
    }

    // ---- reduce att partials across the 4 q-lanes, store from q==0 ----
#pragma unroll
    for (int off = 16; off <= 32; off <<= 1) {
#pragma unroll
        for (int nt = 0; nt < 2; ++nt)
#pragma unroll
            for (int r = 0; r < 4; ++r) {
                s[nt][r] += __shfl_xor(s[nt][r], off, 64);
                d[nt][r] += __shfl_xor(d[nt][r], off, 64);
            }
    }
    if (q == 0) {
#pragma unroll
        for (int nt = 0; nt < 2; ++nt) {
            if (g[nt]) {
                *(float4*)(a_src + (size_t)nodes[nt] * 4) =
                    make_float4(s[nt][0], s[nt][1], s[nt][2], s[nt][3]);
                *(float4*)(a_dst + (size_t)nodes[nt] * 4) =
                    make_float4(d[nt][0], d[nt][1], d[nt][2], d[nt][3]);
            }
        }
    }
}

__global__ __launch_bounds__(256, 2) void k1_gemm(
        const void* __restrict__ x, const bf16* __restrict__ Wbk1,
        const void* __restrict__ resW, const void* __restrict__ resB,
        const void* __restrict__ biasG, const void* __restrict__ attS,
        const void* __restrict__ attD,
        f16* __restrict__ xl, float* __restrict__ out_acc,
        float* __restrict__ a_src, float* __restrict__ a_dst,
        const int* __restrict__ ei, int* __restrict__ cnt,
        int* __restrict__ adj, int NB1, int E, int N) {
    __shared__ char xlbuf[65536];       // xl staging (reused for out_acc)
    __shared__ bf16 aSc[HC], aDc[HC];
    const int t = threadIdx.x;

    if (blockIdx.x >= NB1) {
        // ---- scatter blocks: capacity-CSR build, 4 edges/thread ----
        const long long base = (long long)(blockIdx.x - NB1) * 1024;
        const bool w64 = sniff_i64(ei);
#pragma unroll
        for (int u = 0; u < 4; ++u) {
            long long e = base + u * 256 + t;
            if (e < E) {
                int s = gidx(ei, e, w64, N);
                int d = gidx(ei, (long long)E + e, w64, N);
                int pos = atomicAdd(&cnt[d], 1);
                if (pos < CAP)
                    __builtin_nontemporal_store(s, &adj[(size_t)d * CAP + pos]);
            }
        }
        return;
    }

    const bool f32 = sniff_f32(x);
    {   // stage att channel-major: aSc[e] = attS[(e&3)*64 + (e>>2)]
        int src = (t & 3) * 64 + (t >> 2);
        aSc[t] = f32 ? (bf16)((const float*)attS)[src] : ((const bf16*)attS)[src];
        aDc[t] = f32 ? (bf16)((const float*)attD)[src] : ((const bf16*)attD)[src];
    }
    __syncthreads();
    if (f32) k1_impl<true >(x, (const bf16x8*)Wbk1, resW, resB, biasG, aSc, aDc, xlbuf, xl, out_acc, a_src, a_dst, N);
    else     k1_impl<false>(x, (const bf16x8*)Wbk1, resW, resB, biasG, aSc, aDc, xlbuf, xl, out_acc, a_src, a_dst, N);
}

// ---------------------------------------------------------------------------
// K3: fused softmax + aggregation over capacity-CSR. One wave per node.
//     R13-proven kernel: f16 xl + fdot2, half-wave dwordx4 row loads,
//     pre-normalized f16 weights, self-loop as edge slot cn. ~107us floor.
// ---------------------------------------------------------------------------
__global__ __launch_bounds__(256) void k3_fused(
        const int* __restrict__ cnt, const int* __restrict__ adj,
        const float* __restrict__ a_src, const float* __restrict__ a_dst,
        const f16* __restrict__ xl, float* __restrict__ out_acc, int N) {
    __shared__ unsigned sh_w[4][64][2];   // normalized f16x4 weights per entry
    __shared__ int      sh_off[4][64];    // row byte offsets (s*512)
    const int wid  = threadIdx.x >> 6;
    const int lane = threadIdx.x & 63;
    const int n = blockIdx.x * 4 + wid;
    if (n >= N) return;
    int cn = cnt[n]; if (cn > CAP) cn = CAP;
    const float4 ad  = *(const float4*)(a_dst + (size_t)n * 4);
    const float4 asn = *(const float4*)(a_src + (size_t)n * 4);
    const float e0 = eexp(lrelu(asn.x + ad.x));
    const float e1 = eexp(lrelu(asn.y + ad.y));
    const float e2 = eexp(lrelu(asn.z + ad.z));
    const float e3 = eexp(lrelu(asn.w + ad.w));

    float w0 = 0.f, w1 = 0.f, w2 = 0.f, w3 = 0.f;
    float d0 = 0.f, d1 = 0.f, d2 = 0.f, d3 = 0.f;
    int s = 0;
    if (lane < cn) {
        s = adj[(size_t)n * CAP + lane];
        float4 as = *(const float4*)(a_src + (size_t)s * 4);
        w0 = eexp(lrelu(as.x + ad.x));
        w1 = eexp(lrelu(as.y + ad.y));
        w2 = eexp(lrelu(as.z + ad.z));
        w3 = eexp(lrelu(as.w + ad.w));
        d0 = w0; d1 = w1; d2 = w2; d3 = w3;
    }
    // wave-reduce denominators, add self, fold 0.25 head-mean into inverse
#pragma unroll
    for (int off = 1; off <= 32; off <<= 1) {
        d0 += __shfl_xor(d0, off, 64);
        d1 += __shfl_xor(d1, off, 64);
        d2 += __shfl_xor(d2, off, 64);
        d3 += __shfl_xor(d3, off, 64);
    }
    d0 += e0; d1 += e1; d2 += e2; d3 += e3;
    const float i0 = 0.25f * __builtin_amdgcn_rcpf(d0);
    const float i1 = 0.25f * __builtin_amdgcn_rcpf(d1);
    const float i2 = 0.25f * __builtin_amdgcn_rcpf(d2);
    const float i3 = 0.25f * __builtin_amdgcn_rcpf(d3);

    if (lane < cn) {
        h2 wa; wa[0] = (f16)(w0 * i0); wa[1] = (f16)(w1 * i1);
        h2 wb; wb[0] = (f16)(w2 * i2); wb[1] = (f16)(w3 * i3);
        sh_w[wid][lane][0] = __builtin_bit_cast(unsigned, wa);
        sh_w[wid][lane][1] = __builtin_bit_cast(unsigned, wb);
        sh_off[wid][lane] = s << 9;           // s * HC * sizeof(f16)
    } else if (lane == cn) {                   // self-loop as edge slot cn
        h2 wa; wa[0] = (f16)(e0 * i0); wa[1] = (f16)(e1 * i1);
        h2 wb; wb[0] = (f16)(e2 * i2); wb[1] = (f16)(e3 * i3);
        sh_w[wid][cn][0] = __builtin_bit_cast(unsigned, wa);
        sh_w[wid][cn][1] = __builtin_bit_cast(unsigned, wb);
        sh_off[wid][cn] = n << 9;
    }

    const int m = cn + 1;                      // entries incl. self
    const int half = lane >> 5, l32 = lane & 31;
    // lane owns channels (2*l32, 2*l32+1); half selects row within a pair
    const char* xb = (const char*)xl + l32 * 16;
    float acc0 = 0.f, acc1 = 0.f;

#define K3DOT(raw, wr) do {                                              \
        h2 va = bch2((raw).x), vb = bch2((raw).y);                       \
        h2 vc = bch2((raw).z), vd = bch2((raw).w);                       \
        h2 wa = bch2((wr).x),  wb = bch2((wr).y);                        \
        acc0 = dot2h(va, wa, acc0); acc0 = dot2h(vb, wb, acc0);          \
        acc1 = dot2h(vc, wa, acc1); acc1 = dot2h(vd, wb, acc1);          \
    } while (0)

    int j = 0;
    for (; j + 4 <= m; j += 4) {               // 2 pairs in flight
        int offA = sh_off[wid][j + half];
        int offB = sh_off[wid][j + 2 + half];
        uint4 ra = *(const uint4*)(xb + offA);
        uint4 rb = *(const uint4*)(xb + offB);
        uint2 wA = *(const uint2*)&sh_w[wid][j + half][0];
        uint2 wB = *(const uint2*)&sh_w[wid][j + 2 + half][0];
        K3DOT(ra, wA);
        K3DOT(rb, wB);
    }
    if (j + 2 <= m) {                          // one pair
        int offA = sh_off[wid][j + half];
        uint4 ra = *(const uint4*)(xb + offA);
        uint2 wA = *(const uint2*)&sh_w[wid][j + half][0];
        K3DOT(ra, wA);
        j += 2;
    }
    if (j < m && half == 0) {                  // odd tail: half0 only
        int offA = sh_off[wid][j];
        uint4 ra = *(const uint4*)(xb + offA);
        uint2 wA = *(const uint2*)&sh_w[wid][j][0];
        K3DOT(ra, wA);
    }
#undef K3DOT

    acc0 += __shfl_xor(acc0, 32, 64);
    acc1 += __shfl_xor(acc1, 32, 64);
    if (half == 0) {
        float2* p = (float2*)(out_acc + (size_t)n * CDIM + l32 * 2);
        float2 v = *p;
        v.x += acc0; v.y += acc1;
        *p = v;                                // seeded with residual + biases
    }
}

// ---------------------------------------------------------------------------
// K4: GraphNorm partial sums, atomic finish; block 0 computes start[].
// ---------------------------------------------------------------------------
__global__ __launch_bounds__(256) void k4_stats(
        const float* __restrict__ out_acc, const int* __restrict__ batch,
        const int* __restrict__ ei,
        float* __restrict__ S1, float* __restrict__ S2,
        int* __restrict__ start, int N) {
    __shared__ float p1[4][BGRAPH][64], p2[4][BGRAPH][64];
    const int w = threadIdx.x >> 6;
    const int c = threadIdx.x & 63;
#pragma unroll
    for (int k = threadIdx.x; k < 4 * BGRAPH * 64; k += 256) {
        ((float*)p1)[k] = 0.f; ((float*)p2)[k] = 0.f;
    }
    __syncthreads();
    bool w64 = sniff_i64(ei);
    const int n0 = blockIdx.x * 256 + w * 64;
    float ls1 = 0.f, ls2 = 0.f;
    int curb = -1;
    for (int i = 0; i < 64; ++i) {
        int n = n0 + i;
        if (n >= N) break;
        float hv = out_acc[(size_t)n * CDIM + c];
        int b = gidx(batch, n, w64, BGRAPH);
        if (b != curb) {
            if (curb >= 0) { p1[w][curb][c] += ls1; p2[w][curb][c] += ls2; }
            curb = b; ls1 = 0.f; ls2 = 0.f;
        }
        ls1 += hv; ls2 += hv * hv;
    }
    if (curb >= 0) { p1[w][curb][c] += ls1; p2[w][curb][c] += ls2; }
    __syncthreads();
    for (int k = threadIdx.x; k < BGRAPH * 64; k += 256) {
        int b = k >> 6, cc = k & 63;
        float v1 = p1[0][b][cc] + p1[1][b][cc] + p1[2][b][cc] + p1[3][b][cc];
        float v2 = p2[0][b][cc] + p2[1][b][cc] + p2[2][b][cc] + p2[3][b][cc];
        if (v1 != 0.f) atomicAdd(&S1[k], v1);
        if (v2 != 0.f) atomicAdd(&S2[k], v2);
    }
    if (blockIdx.x == 0 && threadIdx.x <= BGRAPH) {
        int t = threadIdx.x;
        int lo = 0, hi = N;
        while (lo < hi) {
            int mid = (lo + hi) >> 1;
            long long bv = w64 ? ((const long long*)batch)[mid] : (long long)batch[mid];
            if (bv < t) lo = mid + 1; else hi = mid;
        }
        start[t] = lo;
    }
}

// ---------------------------------------------------------------------------
// K6: GraphNorm + GELU(tanh approx) -> out (dtype per sniff)
// ---------------------------------------------------------------------------
template <bool F32>
__device__ __forceinline__ void k6_impl(
        const float* __restrict__ out_acc, const int* __restrict__ batch,
        bool w64,
        const float* __restrict__ S1, const float* __restrict__ S2,
        const int* __restrict__ start, const void* __restrict__ gw,
        const void* __restrict__ gb, const void* __restrict__ msc,
        void* __restrict__ out, int N) {
    int idx = blockIdx.x * 256 + threadIdx.x;
    if (idx >= N * CDIM) return;
    int n = idx >> 6, c = idx & 63;
    int b = gidx(batch, n, w64, BGRAPH);
    int cnt_i = start[b + 1] - start[b];
    float cnt = (float)(cnt_i < 1 ? 1 : cnt_i);
    float m = S1[b * CDIM + c] / cnt;
    float ms = ldf<F32>(msc, c);
    float var = S2[b * CDIM + c] / cnt + m * m * ms * (ms - 2.0f);
    float centered = out_acc[idx] - m * ms;
    float normed = ldf<F32>(gw, c) * centered * rsqrtf(fmaxf(var, 0.f) + EPS_GN)
                   + ldf<F32>(gb, c);
    float t = 0.7978845608028654f * (normed + 0.044715f * normed * normed * normed);
    float gel = 0.5f * normed * (1.0f + tanhf(t));
    if constexpr (F32) ((float*)out)[idx] = gel;
    else               ((bf16*)out)[idx] = (bf16)gel;
}

__global__ __launch_bounds__(256) void k6_norm(
        const void* __restrict__ xsniff,
        const float* __restrict__ out_acc, const int* __restrict__ batch,
        const int* __restrict__ ei,
        const float* __restrict__ S1, const float* __restrict__ S2,
        const int* __restrict__ start, const void* __restrict__ gw,
        const void* __restrict__ gb, const void* __restrict__ msc,
        void* __restrict__ out, int N) {
    bool w64 = sniff_i64(ei);
    if (sniff_f32(xsniff))
        k6_impl<true >(out_acc, batch, w64, S1, S2, start, gw, gb, msc, out, N);
    else
        k6_impl<false>(out_acc, batch, w64, S1, S2, start, gw, gb, msc, out, N);
}

// ---------------------------------------------------------------------------
extern "C" void kernel_launch(void* const* d_in, const int* in_sizes, int n_in,
                              void* d_out, int out_size, void* d_ws, size_t ws_size,
                              hipStream_t stream) {
    const void* x     = d_in[0];
    const int*  ei    = (const int*)d_in[1];
    const int*  batch = (const int*)d_in[2];
    const void* W     = d_in[3];
    const void* attS  = d_in[4];
    const void* attD  = d_in[5];
    const void* biasG = d_in[6];
    const void* resW  = d_in[7];
    const void* resB  = d_in[8];
    const void* gw    = d_in[9];
    const void* gb    = d_in[10];
    const void* msc   = d_in[11];

    const int N = in_sizes[0] / FIN;
    const int E = in_sizes[1] / 2;
    const int NB = (N + 255) / 256;    // 256-node blocks (k4)
    const int NB1 = (N + 127) / 128;   // GEMM blocks in fused k1
    const int NBS = (E + 1023) / 1024; // scatter blocks in fused k1

    char* ws = (char*)d_ws;
    size_t off = 0;
    auto alloc = [&](size_t bytes) { char* p = ws + off; off = (off + bytes + 255) & ~(size_t)255; return p; };
    f16*   xl      = (f16*)  alloc((size_t)N * HC * sizeof(f16));
    float* out_acc = (float*)alloc((size_t)N * CDIM * sizeof(float));
    float* a_src   = (float*)alloc((size_t)N * HEADS * sizeof(float));
    float* a_dst   = (float*)alloc((size_t)N * HEADS * sizeof(float));
    int*   cnt     = (int*)  alloc((size_t)N * sizeof(int));
    float* S1      = (float*)alloc(BGRAPH * CDIM * sizeof(float));
    float* S2      = (float*)alloc(BGRAPH * CDIM * sizeof(float));
    int*   adj     = (int*)  alloc((size_t)N * CAP * sizeof(int));
    bf16*  Wbk1    = (bf16*) alloc((size_t)HC * FIN * sizeof(bf16));   // 64 KB
    int*   start   = (int*)  alloc((BGRAPH + 1) * sizeof(int));

    hipLaunchKernelGGL(kz_zero, dim3((N + 255) / 256), dim3(256), 0, stream,
                       cnt, S1, S2, W, Wbk1, N);
    hipLaunchKernelGGL(k1_gemm, dim3(NB1 + NBS), dim3(256), 0, stream,
                       x, Wbk1, resW, resB, biasG, attS, attD, xl, out_acc,
                       a_src, a_dst, ei, cnt, adj, NB1, E, N);
    hipLaunchKernelGGL(k3_fused, dim3((N + 3) / 4), dim3(256), 0, stream,
                       cnt, adj, a_src, a_dst, xl, out_acc, N);
    hipLaunchKernelGGL(k4_stats, dim3(NB), dim3(256), 0, stream,
                       out_acc, batch, ei, S1, S2, start, N);
    hipLaunchKernelGGL(k6_norm, dim3((N * CDIM + 255) / 256), dim3(256), 0, stream,
                       x, out_acc, batch, ei, S1, S2, start, gw, gb, msc, d_out, N);
}